// Round 19
// baseline (1229.932 us; speedup 1.0000x reference)
//
// CaptionDecoder on MI355X — round 19: FW slice parked in REGISTERS.
// r18: D-ctx streamed 51.4MB/step of FW (FETCH 912MB, ~5-6us/step). But each
// thread reads the SAME 98 FW values every step -> load once into fwreg[98]
// in the prologue; D-ctx becomes a zero-memory 98-FMA register contraction.
// ~215 VGPRs, still 2 waves/SIMD.
#include <hip/hip_runtime.h>

#define E 512
#define H 512
#define V 32000
#define B 32
#define P 196
#define T 32
#define NB 256
#define NT 512

typedef __attribute__((ext_vector_type(8))) short s8v;    // 8 bf16
typedef __attribute__((ext_vector_type(4))) float f4v;    // 4 f32 acc

__device__ __forceinline__ float bf16_to_f(unsigned short u){
  return __uint_as_float(((unsigned)u) << 16);
}
__device__ __forceinline__ unsigned short f_to_bf16(float f){
  unsigned u = __float_as_uint(f);
  u += 0x7FFFu + ((u >> 16) & 1u);   // RNE
  return (unsigned short)(u >> 16);
}
__device__ __forceinline__ float fast_tanh(float x){
  float e = __expf(2.0f*x);
  return 1.0f - 2.0f/(e + 1.0f);
}
__device__ __forceinline__ float sigmoidf_(float x){
  return 1.0f/(1.0f + __expf(-x));
}
__device__ __forceinline__ void load_lds16(const unsigned short* g, unsigned short* l){
  __builtin_amdgcn_global_load_lds(
      (const __attribute__((address_space(1))) void*)g,
      (__attribute__((address_space(3))) void*)l, 16, 0, 0);
}
__device__ __forceinline__ float dot4(float4 a, float4 b){
  return a.x*b.x + a.y*b.y + a.z*b.z + a.w*b.w;
}

#define AT_SCOPE __HIP_MEMORY_SCOPE_AGENT
__device__ __forceinline__ void cohstore(float* p, float v){
  __hip_atomic_store(p, v, __ATOMIC_RELAXED, AT_SCOPE);
}
__device__ __forceinline__ unsigned cohldu(const unsigned* p){
  return __hip_atomic_load(p, __ATOMIC_RELAXED, AT_SCOPE);
}
__device__ __forceinline__ void cohstu(unsigned* p, unsigned v){
  __hip_atomic_store(p, v, __ATOMIC_RELAXED, AT_SCOPE);
}

// 8-block mini-barrier, split arrive/wait (all relaxed; __syncthreads drains
// vmcnt -> block's coherent stores are LLC-visible before the flag publish).
__device__ __forceinline__ void bar_arrive(unsigned* my, unsigned gen){
  __syncthreads();
  if (threadIdx.x == 0) cohstu(my, gen);
}
__device__ __forceinline__ void bar_wait(const unsigned* base, unsigned gen){
  if (threadIdx.x < 64){
    for (;;){
      unsigned mn = 0xffffffffu;
      for (int i = (int)threadIdx.x; i < 8; i += 64){
        unsigned v = cohldu(base + i);
        mn = v < mn ? v : mn;
      }
      #pragma unroll
      for (int off = 32; off; off >>= 1){
        unsigned o2 = (unsigned)__shfl_xor((int)mn, off);
        mn = o2 < mn ? o2 : mn;
      }
      if (mn >= gen) break;
      __builtin_amdgcn_s_sleep(1);
    }
    __builtin_amdgcn_sched_barrier(0);
  }
  __syncthreads();
}

// ---------------------------------------------------------------------------
// f32 (strided) -> bf16 hi (+ optional lo residual). cols==512.
__global__ void split_kernel(const float* __restrict__ src, int src_ld, int src_coff,
                             int rows,
                             unsigned short* __restrict__ dhi, unsigned short* __restrict__ dlo,
                             int dst_ld, int dst_coff)
{
  int n = rows << 9;
  for (int i = blockIdx.x*blockDim.x + threadIdx.x; i < n; i += gridDim.x*blockDim.x){
    int r = i >> 9, c = i & 511;
    float x = src[(size_t)r*src_ld + src_coff + c];
    unsigned short h = f_to_bf16(x);
    dhi[(size_t)r*dst_ld + dst_coff + c] = h;
    if (dlo) dlo[(size_t)r*dst_ld + dst_coff + c] = f_to_bf16(x - bf16_to_f(h));
  }
}

// Embedding gather -> bf16 hi/lo rows (row = b*T + t)
__global__ void embed_kernel(const int* __restrict__ caps, const float* __restrict__ embW,
                             unsigned short* __restrict__ ehi, unsigned short* __restrict__ elo)
{
  int row = blockIdx.x;
  int cap = caps[row];
  const float* s = embW + (size_t)cap*E;
  for (int e = threadIdx.x; e < E; e += blockDim.x){
    float x = s[e];
    unsigned short h = f_to_bf16(x);
    ehi[(size_t)row*E + e] = h;
    elo[(size_t)row*E + e] = f_to_bf16(x - bf16_to_f(h));
  }
}

// mean over P, then h0 -> hgrp[0][b], c0 -> c_state
__global__ __launch_bounds__(512) void prep_kernel(
    const float* __restrict__ feats,
    const float* __restrict__ inith_W, const float* __restrict__ inith_b,
    const float* __restrict__ initc_W, const float* __restrict__ initc_b,
    float* __restrict__ hgrp, float* __restrict__ c_state)
{
  __shared__ float mf[E];
  const int b = blockIdx.x, tid = threadIdx.x;
  const float* fb = feats + (size_t)b*P*E + tid;
  float s = 0.f;
  for (int p = 0; p < P; ++p) s += fb[(size_t)p*E];
  mf[tid] = s * (1.0f/196.0f);
  __syncthreads();
  const float* wh = inith_W + (size_t)tid*E;
  const float* wc = initc_W + (size_t)tid*E;
  float h0 = inith_b[tid], c0 = initc_b[tid];
  #pragma unroll 4
  for (int e = 0; e < E; e += 4){
    float4 a4 = *(const float4*)(wh + e);
    float4 b4 = *(const float4*)(wc + e);
    float4 m4 = *(const float4*)(mf + e);
    h0 += dot4(a4, m4);
    c0 += dot4(b4, m4);
  }
  hgrp[(size_t)b*512 + tid] = h0;
  c_state[b*512 + tid] = c0;
}

// WhT[k][j] = attn_W[j][E + k]
__global__ __launch_bounds__(256) void transpose_wh_kernel(
    const float* __restrict__ attn_W, float* __restrict__ WhT)
{
  __shared__ float tile[64][65];
  const int jt = blockIdx.x & 7, kt = blockIdx.x >> 3;
  const int tx = threadIdx.x & 63, ty = threadIdx.x >> 6;
  for (int r = ty; r < 64; r += 4)
    tile[r][tx] = attn_W[(size_t)(jt*64 + r)*(E+H) + E + kt*64 + tx];
  __syncthreads();
  for (int r = ty; r < 64; r += 4)
    WhT[(size_t)(kt*64 + r)*512 + jt*64 + tx] = tile[tx][r];
}

// Wpackh[sub][k][c]: k in [0,512) = Whh row of gate col; c in [0,256):
// gcol = (c>>6)*512 + sub*64 + (c&63). Coalesced repack.
__global__ __launch_bounds__(256) void pack_whh_kernel(
    const float* __restrict__ Whh, float* __restrict__ Wpackh)
{
  __shared__ float tile[64][65];
  const int sub = blockIdx.x & 7, cg = (blockIdx.x >> 3) & 3, kg = blockIdx.x >> 5;
  const int tx = threadIdx.x & 63, ty = threadIdx.x >> 6;
  const int kbase = kg*64;
  for (int cl = ty; cl < 64; cl += 4){
    const int c = cg*64 + cl;
    const int gcol = (c >> 6)*512 + sub*64 + (c & 63);
    tile[cl][tx] = Whh[(size_t)gcol*512 + kbase + tx];
  }
  __syncthreads();
  for (int kk = ty; kk < 64; kk += 4)
    Wpackh[((size_t)sub*512 + kbase + kk)*256 + cg*64 + tx] = tile[tx][kk];
}

// ---------------------------------------------------------------------------
// m97-style bf16 GEMM: C = sum_passes A_p (MxK) * B_p(NxK)^T [+bias]
__global__ __launch_bounds__(256) void gemm_bt_kernel(
    const unsigned short* __restrict__ A0, const unsigned short* __restrict__ A1,
    const unsigned short* __restrict__ A2,
    const unsigned short* __restrict__ B0, const unsigned short* __restrict__ B1,
    const unsigned short* __restrict__ B2,
    float* __restrict__ Cc, const float* __restrict__ bias,
    int N, int K, int npasses, int mt, int swz)
{
  __shared__ __align__(16) unsigned short Al[128*32];
  __shared__ __align__(16) unsigned short Bl[128*32];
  const int tid = threadIdx.x;
  const int wid = tid >> 6, l = tid & 63;
  int f = blockIdx.x;
  if (swz) f = (f & 7)*((int)gridDim.x >> 3) + (f >> 3);
  const int m0 = (f % mt)*128, n0 = (f / mt)*128;
  const int wr = wid >> 1, wc = wid & 1;

  f4v acc[4][4];
  #pragma unroll
  for (int i = 0; i < 4; ++i)
    #pragma unroll
    for (int j = 0; j < 4; ++j) acc[i][j] = (f4v){0.f,0.f,0.f,0.f};

  const int s0 = tid, s1 = tid + 256;
  const int r0 = s0 >> 2, g0 = (s0 & 3) ^ ((r0 >> 1) & 3);
  const int r1 = s1 >> 2, g1 = (s1 & 3) ^ ((r1 >> 1) & 3);
  const int la = l & 15, ch = l >> 4;

  for (int pass = 0; pass < npasses; ++pass){
    const unsigned short* Ap = pass == 0 ? A0 : (pass == 1 ? A1 : A2);
    const unsigned short* Bp = pass == 0 ? B0 : (pass == 1 ? B1 : B2);
    for (int k0 = 0; k0 < K; k0 += 32){
      __syncthreads();
      load_lds16(Ap + (size_t)(m0 + r0)*K + k0 + g0*8, Al + s0*8);
      load_lds16(Ap + (size_t)(m0 + r1)*K + k0 + g1*8, Al + s1*8);
      load_lds16(Bp + (size_t)(n0 + r0)*K + k0 + g0*8, Bl + s0*8);
      load_lds16(Bp + (size_t)(n0 + r1)*K + k0 + g1*8, Bl + s1*8);
      __syncthreads();
      s8v av[4], bv[4];
      #pragma unroll
      for (int mi = 0; mi < 4; ++mi){
        int row = wr*64 + mi*16 + la;
        int cs = ch ^ ((row >> 1) & 3);
        av[mi] = *(const s8v*)(Al + (row*4 + cs)*8);
      }
      #pragma unroll
      for (int ni = 0; ni < 4; ++ni){
        int row = wc*64 + ni*16 + la;
        int cs = ch ^ ((row >> 1) & 3);
        bv[ni] = *(const s8v*)(Bl + (row*4 + cs)*8);
      }
      #pragma unroll
      for (int mi = 0; mi < 4; ++mi)
        #pragma unroll
        for (int ni = 0; ni < 4; ++ni)
          acc[mi][ni] = __builtin_amdgcn_mfma_f32_16x16x32_bf16(av[mi], bv[ni], acc[mi][ni], 0, 0, 0);
    }
  }
  #pragma unroll
  for (int mi = 0; mi < 4; ++mi){
    int row = m0 + wr*64 + mi*16 + (l >> 4)*4;
    #pragma unroll
    for (int ni = 0; ni < 4; ++ni){
      int col = n0 + wc*64 + ni*16 + (l & 15);
      float bb = bias ? bias[col] : 0.0f;
      #pragma unroll
      for (int r = 0; r < 4; ++r)
        Cc[(size_t)(row + r)*N + col] = acc[mi][ni][r] + bb;
    }
  }
}

// ---------------------------------------------------------------------------
// Persistent loop kernel, batch-local groups, zero global sync, 2 minis/step.
// blk = b*8 + sub. Block owns j-slice sub*64..+64 x 4 gates of ITS batch.
// FW slice (98 step-invariant values/thread) lives in REGISTERS -> D-ctx is a
// zero-memory 98-FMA contraction. D-h streams Wpackh[sub] (0.5MB, L2-res).
// Per step: [ge pf] A,B | arrive1 | D-h | wait1 | softmax | D-ctx | update |
//           arrive3 | hall stores | wait3.
__global__ __launch_bounds__(512, 1) void loop_kernel(
    const float* __restrict__ feat_proj,
    const float* __restrict__ WhT, const float* __restrict__ attn_b,
    const float* __restrict__ v_w, const float* __restrict__ Wpackh,
    const float* __restrict__ FW, const float* __restrict__ gates_emb,
    const float* __restrict__ b_ih, const float* __restrict__ b_hh,
    float* __restrict__ hgrp,          // [T+1][B][512]
    const float* __restrict__ c_init,
    float* __restrict__ sps,           // [T][B][200][8]
    unsigned short* __restrict__ hall_h, unsigned short* __restrict__ hall_l,
    unsigned* __restrict__ fm1, unsigned* __restrict__ fm3)
{
  __shared__ float hs[512];
  __shared__ float hwl[64];
  __shared__ float partA[8][72];
  __shared__ float aux[256];
  __shared__ float biasl[256];
  __shared__ float red[512];
  __shared__ float smx, sinv;

  const int blk = blockIdx.x, tid = threadIdx.x;
  const int b = blk >> 3, sub = blk & 7;
  const int gbase = blk & ~7;
  const int l = tid & 63, wv = tid >> 6;

  // ---- prologue ----
  float wreg[64];
  #pragma unroll
  for (int kk = 0; kk < 64; ++kk)
    wreg[kk] = WhT[(size_t)(wv*64 + kk)*512 + sub*64 + l];
  float fpreg[25];
  #pragma unroll
  for (int i = 0; i < 25; ++i){
    const int p = wv + i*8;
    fpreg[i] = (p < P) ? feat_proj[((size_t)b*P + p)*512 + sub*64 + l] : 0.f;
  }
  for (int c = tid; c < 256; c += NT){
    const int gcol = (c >> 6)*512 + sub*64 + (c & 63);
    biasl[c] = b_ih[gcol] + b_hh[gcol];
  }
  const float vl = v_w[sub*64 + l];
  const float ab = (tid < 64) ? attn_b[sub*64 + tid] : 0.f;
  float c_reg = 0.f;
  if (tid < 64) c_reg = c_init[b*512 + sub*64 + tid];

  // phase-D decomposition: thread = (dc: block-local col, kh: half)
  const int dc = tid & 255;
  const int kh = tid >> 8;
  const int gcol_d = (dc >> 6)*512 + sub*64 + (dc & 63);
  const float* wp_h = Wpackh + ((size_t)sub*512 + kh*256)*256 + dc;

  // FW slice -> registers (step-invariant: same 98 values every step)
  float fwreg[98];
  {
    const float* fwb = FW + ((size_t)b*P + kh*98)*2048 + gcol_d;
    #pragma unroll
    for (int i = 0; i < 98; ++i) fwreg[i] = fwb[(size_t)i*2048];
  }
  __syncthreads();

  for (int t = 0; t < T; ++t){
    const unsigned gen = (unsigned)(t + 1);

    // ---- gates_emb prefetch (hidden under A/B/D-h) ----
    float gepre[4];
    if (tid < 64){
      const float* ge = gates_emb + ((size_t)b*T + t)*2048;
      #pragma unroll
      for (int g = 0; g < 4; ++g) gepre[g] = ge[g*512 + sub*64 + tid];
    }

    // ---- A: hWh[b][sub*64..+64) (register WhT slice x LDS-broadcast h) ----
    hs[tid] = hgrp[((size_t)t*B + b)*512 + tid];      // plain (time-indexed)
    __syncthreads();
    {
      const float* hk = hs + wv*64;
      float a = 0.f;
      #pragma unroll
      for (int kk = 0; kk < 64; ++kk) a += hk[kk] * wreg[kk];
      partA[wv][l] = a;
    }
    __syncthreads();
    if (tid < 64){
      float s = ab;
      #pragma unroll
      for (int k = 0; k < 8; ++k) s += partA[k][tid];
      hwl[tid] = s;
    }
    __syncthreads();

    // ---- B: partial scores over own j-slice (feat_proj from registers) ----
    {
      const float hj = hwl[l];
      float* spw = sps + (size_t)(t*B + b)*1600 + sub;
      #pragma unroll
      for (int i = 0; i < 25; ++i){
        const int p = wv + i*8;
        if (p >= P) break;
        float e2 = vl * fast_tanh(fpreg[i] + hj);
        #pragma unroll
        for (int off = 32; off; off >>= 1) e2 += __shfl_xor(e2, off);
        if (l == 0) cohstore(spw + p*8, e2);
      }
    }
    bar_arrive(fm1 + blk, gen);

    // ---- D-h: Whh-part dots (needs only hs; hides mini1 window) ----
    float acch0 = 0.f, acch1 = 0.f, acch2 = 0.f, acch3 = 0.f;
    {
      const float* hk = hs + kh*256;
      #pragma unroll 8
      for (int k = 0; k < 256; k += 4){
        acch0 += wp_h[(size_t)(k+0)*256] * hk[k+0];
        acch1 += wp_h[(size_t)(k+1)*256] * hk[k+1];
        acch2 += wp_h[(size_t)(k+2)*256] * hk[k+2];
        acch3 += wp_h[(size_t)(k+3)*256] * hk[k+3];
      }
    }
    bar_wait(fm1 + gbase, gen);

    // ---- softmax (redundant x8, all operands local/plain) ----
    {
      float sc_v = -1e30f;
      if (tid < P){
        const float* sp = sps + (size_t)(t*B + b)*1600 + tid*8;
        float4 q0 = *(const float4*)sp, q1 = *(const float4*)(sp + 4);
        sc_v = (q0.x + q0.y + q0.z + q0.w) + (q1.x + q1.y + q1.z + q1.w);
      }
      if (tid < 256) aux[tid] = sc_v;
      __syncthreads();
      if (tid < 64){
        float m = -1e30f;
        #pragma unroll
        for (int i = 0; i < 4; ++i) m = fmaxf(m, aux[tid + i*64]);
        #pragma unroll
        for (int off = 32; off; off >>= 1) m = fmaxf(m, __shfl_xor(m, off));
        if (tid == 0) smx = m;
      }
      __syncthreads();
      float al = (tid < P) ? __expf(sc_v - smx) : 0.f;
      if (tid < 256) aux[tid] = al;
      __syncthreads();
      if (tid < 64){
        float s = 0.f;
        #pragma unroll
        for (int i = 0; i < 4; ++i) s += aux[tid + i*64];
        #pragma unroll
        for (int off = 32; off; off >>= 1) s += __shfl_xor(s, off);
        if (tid == 0) sinv = 1.0f/s;
      }
      __syncthreads();
    }

    // ---- D-ctx: rank-P contraction, ALL IN REGISTERS ----
    float accc = 0.f;
    {
      const float* ax = aux + kh*98;
      #pragma unroll
      for (int i = 0; i < 98; ++i)
        accc += ax[i] * fwreg[i];
    }
    red[dc*2 + kh] = ((acch0 + acch1) + (acch2 + acch3)) + accc*sinv;
    __syncthreads();

    // ---- LSTM update ----
    if (tid < 64){
      float gv[4];
      #pragma unroll
      for (int g = 0; g < 4; ++g){
        const int c = g*64 + tid;
        gv[g] = red[c*2] + red[c*2 + 1] + biasl[c] + gepre[g];
      }
      const float i_ = sigmoidf_(gv[0]);
      const float f_ = sigmoidf_(gv[1]);
      const float g_ = fast_tanh(gv[2]);
      const float o_ = sigmoidf_(gv[3]);
      const int j = sub*64 + tid;
      const float c_new = f_*c_reg + i_*g_;
      const float h_new = o_*fast_tanh(c_new);
      c_reg = c_new;
      cohstore(hgrp + ((size_t)(t+1)*B + b)*512 + j, h_new);
      const unsigned short hh = f_to_bf16(h_new);
      aux[tid] = __uint_as_float(((unsigned)hh << 16) |
                 (unsigned)f_to_bf16(h_new - bf16_to_f(hh)));
    }
    bar_arrive(fm3 + blk, gen);
    if (tid < 64){
      const unsigned pk = __float_as_uint(aux[tid]);
      const int j = sub*64 + tid;
      hall_h[((size_t)b*T + t)*512 + j] = (unsigned short)(pk >> 16);
      hall_l[((size_t)b*T + t)*512 + j] = (unsigned short)(pk & 0xffffu);
    }
    bar_wait(fm3 + gbase, gen);
  }
}

// ---------------------------------------------------------------------------
extern "C" void kernel_launch(void* const* d_in, const int* in_sizes, int n_in,
                              void* d_out, int out_size, void* d_ws, size_t ws_size,
                              hipStream_t stream)
{
  (void)in_sizes; (void)n_in; (void)out_size;
  const float* features = (const float*)d_in[0];
  const int*   captions = (const int*)d_in[1];
  const float* embed_W  = (const float*)d_in[2];
  const float* attn_W   = (const float*)d_in[3];
  const float* attn_b   = (const float*)d_in[4];
  const float* v_w      = (const float*)d_in[5];
  const float* W_ih     = (const float*)d_in[6];
  const float* W_hh     = (const float*)d_in[7];
  const float* b_ih     = (const float*)d_in[8];
  const float* b_hh     = (const float*)d_in[9];
  const float* lin_W    = (const float*)d_in[10];
  const float* lin_b    = (const float*)d_in[11];
  const float* inith_W  = (const float*)d_in[12];
  const float* inith_b  = (const float*)d_in[13];
  const float* initc_W  = (const float*)d_in[14];
  const float* initc_b  = (const float*)d_in[15];

  // "early" scratch in d_out (~101MB; all dead before final logits GEMM)
  char* o = (char*)d_out;
  unsigned short* feat_hi   = (unsigned short*)o; o += (size_t)(B*P)*E*2;   // 6.4MB
  unsigned short* feat_lo   = (unsigned short*)o; o += (size_t)(B*P)*E*2;   // 6.4MB
  unsigned short* Wf_bf     = (unsigned short*)o; o += (size_t)H*E*2;       // 0.5MB
  float*          feat_proj = (float*)o;          o += (size_t)(B*P)*H*4;   // 12.9MB
  unsigned short* emb_hi    = (unsigned short*)o; o += (size_t)(B*T)*E*2;   // 1.05MB
  unsigned short* emb_lo    = (unsigned short*)o; o += (size_t)(B*T)*E*2;
  unsigned short* Wihe_hi   = (unsigned short*)o; o += (size_t)2048*512*2;  // 2.1MB
  unsigned short* Wihe_lo   = (unsigned short*)o; o += (size_t)2048*512*2;
  unsigned short* Wihc_hi   = (unsigned short*)o; o += (size_t)2048*512*2;  // 2.1MB
  unsigned short* Wihc_lo   = (unsigned short*)o; o += (size_t)2048*512*2;
  float*          gates_emb = (float*)o;          o += (size_t)(B*T)*2048*4;// 8.4MB
  float*          Wpackh    = (float*)o;          o += (size_t)8*512*256*4; // 4.2MB
  float*          FW        = (float*)o;          o += (size_t)(B*P)*2048*4;// 51.4MB

  // persistent scratch in d_ws
  const size_t SZ_LIN  = (size_t)V*H*2;               // 32.77MB
  const size_t SZ_HALL = (size_t)(B*T)*H*2;           // 1MB
  const size_t SZ_HG   = (size_t)(T+1)*B*512*4;       // 2.16MB
  const size_t SZ_SPS  = (size_t)T*B*200*8*4;         // 6.55MB
  const size_t SZ_ST   = (size_t)B*H*4;               // 64KB
  const size_t SZ_WHT  = (size_t)H*H*4;               // 1MB
  const size_t SZ_FLG  = 4096;
  const size_t need_wo = SZ_LIN + 2*SZ_HALL + SZ_HG + SZ_SPS + SZ_ST + SZ_WHT + SZ_FLG;
  const bool three = (ws_size >= need_wo + SZ_LIN);

  char* w = (char*)d_ws;
  unsigned short* lin_hi  = (unsigned short*)w; w += SZ_LIN;
  unsigned short* lin_lo  = (unsigned short*)w; if (three) w += SZ_LIN;
  unsigned short* hall_hi = (unsigned short*)w; w += SZ_HALL;
  unsigned short* hall_lo = (unsigned short*)w; w += SZ_HALL;
  float*          hgrp    = (float*)w;          w += SZ_HG;
  float*          sps     = (float*)w;          w += SZ_SPS;
  float*          c_state = (float*)w;          w += SZ_ST;
  float*          WhT_ws  = (float*)w;          w += SZ_WHT;
  unsigned*       flags   = (unsigned*)w;       w += SZ_FLG;
  unsigned* fm1 = flags;           // [256]
  unsigned* fm3 = flags + 256;     // [256]

  // --- conversions / gathers / packs / init ---
  split_kernel<<<2048, 256, 0, stream>>>(features, E, 0, B*P, feat_hi, feat_lo, E, 0);
  split_kernel<<<256, 256, 0, stream>>>(attn_W, E+H, 0, H, Wf_bf, nullptr, E, 0);
  split_kernel<<<2048, 256, 0, stream>>>(lin_W, 512, 0, V, lin_hi, three ? lin_lo : nullptr, 512, 0);
  split_kernel<<<1024, 256, 0, stream>>>(W_ih, 1024, 0, 2048, Wihe_hi, Wihe_lo, 512, 0);
  split_kernel<<<1024, 256, 0, stream>>>(W_ih, 1024, 512, 2048, Wihc_hi, Wihc_lo, 512, 0);
  embed_kernel<<<B*T, 256, 0, stream>>>(captions, embed_W, emb_hi, emb_lo);
  prep_kernel<<<B, 512, 0, stream>>>(features, inith_W, inith_b, initc_W, initc_b,
                                     hgrp, c_state);
  transpose_wh_kernel<<<64, 256, 0, stream>>>(attn_W, WhT_ws);
  pack_whh_kernel<<<256, 256, 0, stream>>>(W_hh, Wpackh);
  hipMemsetAsync(flags, 0, SZ_FLG, stream);

  // feat_proj = features @ Wf^T (bf16 1-pass; error damped through tanh/softmax)
  gemm_bt_kernel<<<(B*P/128)*(E/128), 256, 0, stream>>>(
      feat_hi, feat_hi, feat_hi, Wf_bf, Wf_bf, Wf_bf,
      feat_proj, nullptr, E, E, 1, B*P/128, 0);
  // gates_emb = emb @ W_ih[:, :512]^T (bf16x3)
  gemm_bt_kernel<<<(B*T/128)*(2048/128), 256, 0, stream>>>(
      emb_hi, emb_lo, emb_hi, Wihe_hi, Wihe_hi, Wihe_lo,
      gates_emb, nullptr, 2048, 512, 3, B*T/128, 1);
  // FW = features @ W_ih[:, 512:]^T (bf16x3) — the ctx-gate precompute
  gemm_bt_kernel<<<(B*P/128)*(2048/128), 256, 0, stream>>>(
      feat_hi, feat_lo, feat_hi, Wihc_hi, Wihc_hi, Wihc_lo,
      FW, nullptr, 2048, 512, 3, B*P/128, 1);

  // --- recurrence: one persistent kernel, zero global sync, 2 minis/step ---
  loop_kernel<<<NB, NT, 0, stream>>>(
      feat_proj, WhT_ws, attn_b, v_w, Wpackh, FW, gates_emb, b_ih, b_hh,
      hgrp, c_state, sps, hall_hi, hall_lo, fm1, fm3);

  // --- logits = h_all @ lin_W^T + lin_b (bf16x3, XCD-swizzled grid) ---
  gemm_bt_kernel<<<(V/128)*(B*T/128), 256, 0, stream>>>(
      hall_hi, hall_lo, hall_hi, lin_hi, lin_hi, three ? lin_lo : lin_hi,
      (float*)d_out, lin_b, V, H, three ? 3 : 2, B*T/128, 1);
}

// Round 20
// 1140.912 us; speedup vs baseline: 1.0780x; 1.0780x over previous
//
// CaptionDecoder on MI355X — round 20: FW hybrid LDS(144 rows f32) + L2-resident stream(52 rows).
// r19 lesson: compiler spills a 98-float register array (VGPR capped at 128) ->
// streaming moved to scratch, regressed. r18's real problem: FW per-XCD
// footprint 6.4MB > 4MB L2 -> per-step LLC/HBM re-miss (FETCH 912MB).
// Fix: 144/196 FW rows in LDS f32 (147KB, conflict-free), remaining 52 rows
// streamed (0.85MB/XCD -> L2-resident). Bit-identical math to r18.
#include <hip/hip_runtime.h>

#define E 512
#define H 512
#define V 32000
#define B 32
#define P 196
#define T 32
#define NB 256
#define NT 512

typedef __attribute__((ext_vector_type(8))) short s8v;    // 8 bf16
typedef __attribute__((ext_vector_type(4))) float f4v;    // 4 f32 acc

__device__ __forceinline__ float bf16_to_f(unsigned short u){
  return __uint_as_float(((unsigned)u) << 16);
}
__device__ __forceinline__ unsigned short f_to_bf16(float f){
  unsigned u = __float_as_uint(f);
  u += 0x7FFFu + ((u >> 16) & 1u);   // RNE
  return (unsigned short)(u >> 16);
}
__device__ __forceinline__ float fast_tanh(float x){
  float e = __expf(2.0f*x);
  return 1.0f - 2.0f/(e + 1.0f);
}
__device__ __forceinline__ float sigmoidf_(float x){
  return 1.0f/(1.0f + __expf(-x));
}
__device__ __forceinline__ void load_lds16(const unsigned short* g, unsigned short* l){
  __builtin_amdgcn_global_load_lds(
      (const __attribute__((address_space(1))) void*)g,
      (__attribute__((address_space(3))) void*)l, 16, 0, 0);
}
__device__ __forceinline__ float dot4(float4 a, float4 b){
  return a.x*b.x + a.y*b.y + a.z*b.z + a.w*b.w;
}

#define AT_SCOPE __HIP_MEMORY_SCOPE_AGENT
__device__ __forceinline__ void cohstore(float* p, float v){
  __hip_atomic_store(p, v, __ATOMIC_RELAXED, AT_SCOPE);
}
__device__ __forceinline__ unsigned cohldu(const unsigned* p){
  return __hip_atomic_load(p, __ATOMIC_RELAXED, AT_SCOPE);
}
__device__ __forceinline__ void cohstu(unsigned* p, unsigned v){
  __hip_atomic_store(p, v, __ATOMIC_RELAXED, AT_SCOPE);
}

// 8-block mini-barrier, split arrive/wait (all relaxed; __syncthreads drains
// vmcnt -> block's coherent stores are LLC-visible before the flag publish).
__device__ __forceinline__ void bar_arrive(unsigned* my, unsigned gen){
  __syncthreads();
  if (threadIdx.x == 0) cohstu(my, gen);
}
__device__ __forceinline__ void bar_wait(const unsigned* base, unsigned gen){
  if (threadIdx.x < 64){
    for (;;){
      unsigned mn = 0xffffffffu;
      for (int i = (int)threadIdx.x; i < 8; i += 64){
        unsigned v = cohldu(base + i);
        mn = v < mn ? v : mn;
      }
      #pragma unroll
      for (int off = 32; off; off >>= 1){
        unsigned o2 = (unsigned)__shfl_xor((int)mn, off);
        mn = o2 < mn ? o2 : mn;
      }
      if (mn >= gen) break;
      __builtin_amdgcn_s_sleep(1);
    }
    __builtin_amdgcn_sched_barrier(0);
  }
  __syncthreads();
}

// ---------------------------------------------------------------------------
// f32 (strided) -> bf16 hi (+ optional lo residual). cols==512.
__global__ void split_kernel(const float* __restrict__ src, int src_ld, int src_coff,
                             int rows,
                             unsigned short* __restrict__ dhi, unsigned short* __restrict__ dlo,
                             int dst_ld, int dst_coff)
{
  int n = rows << 9;
  for (int i = blockIdx.x*blockDim.x + threadIdx.x; i < n; i += gridDim.x*blockDim.x){
    int r = i >> 9, c = i & 511;
    float x = src[(size_t)r*src_ld + src_coff + c];
    unsigned short h = f_to_bf16(x);
    dhi[(size_t)r*dst_ld + dst_coff + c] = h;
    if (dlo) dlo[(size_t)r*dst_ld + dst_coff + c] = f_to_bf16(x - bf16_to_f(h));
  }
}

// Embedding gather -> bf16 hi/lo rows (row = b*T + t)
__global__ void embed_kernel(const int* __restrict__ caps, const float* __restrict__ embW,
                             unsigned short* __restrict__ ehi, unsigned short* __restrict__ elo)
{
  int row = blockIdx.x;
  int cap = caps[row];
  const float* s = embW + (size_t)cap*E;
  for (int e = threadIdx.x; e < E; e += blockDim.x){
    float x = s[e];
    unsigned short h = f_to_bf16(x);
    ehi[(size_t)row*E + e] = h;
    elo[(size_t)row*E + e] = f_to_bf16(x - bf16_to_f(h));
  }
}

// mean over P, then h0 -> hgrp[0][b], c0 -> c_state
__global__ __launch_bounds__(512) void prep_kernel(
    const float* __restrict__ feats,
    const float* __restrict__ inith_W, const float* __restrict__ inith_b,
    const float* __restrict__ initc_W, const float* __restrict__ initc_b,
    float* __restrict__ hgrp, float* __restrict__ c_state)
{
  __shared__ float mf[E];
  const int b = blockIdx.x, tid = threadIdx.x;
  const float* fb = feats + (size_t)b*P*E + tid;
  float s = 0.f;
  for (int p = 0; p < P; ++p) s += fb[(size_t)p*E];
  mf[tid] = s * (1.0f/196.0f);
  __syncthreads();
  const float* wh = inith_W + (size_t)tid*E;
  const float* wc = initc_W + (size_t)tid*E;
  float h0 = inith_b[tid], c0 = initc_b[tid];
  #pragma unroll 4
  for (int e = 0; e < E; e += 4){
    float4 a4 = *(const float4*)(wh + e);
    float4 b4 = *(const float4*)(wc + e);
    float4 m4 = *(const float4*)(mf + e);
    h0 += dot4(a4, m4);
    c0 += dot4(b4, m4);
  }
  hgrp[(size_t)b*512 + tid] = h0;
  c_state[b*512 + tid] = c0;
}

// WhT[k][j] = attn_W[j][E + k]
__global__ __launch_bounds__(256) void transpose_wh_kernel(
    const float* __restrict__ attn_W, float* __restrict__ WhT)
{
  __shared__ float tile[64][65];
  const int jt = blockIdx.x & 7, kt = blockIdx.x >> 3;
  const int tx = threadIdx.x & 63, ty = threadIdx.x >> 6;
  for (int r = ty; r < 64; r += 4)
    tile[r][tx] = attn_W[(size_t)(jt*64 + r)*(E+H) + E + kt*64 + tx];
  __syncthreads();
  for (int r = ty; r < 64; r += 4)
    WhT[(size_t)(kt*64 + r)*512 + jt*64 + tx] = tile[tx][r];
}

// Wpackh[sub][k][c]: k in [0,512) = Whh row of gate col; c in [0,256):
// gcol = (c>>6)*512 + sub*64 + (c&63). Coalesced repack.
__global__ __launch_bounds__(256) void pack_whh_kernel(
    const float* __restrict__ Whh, float* __restrict__ Wpackh)
{
  __shared__ float tile[64][65];
  const int sub = blockIdx.x & 7, cg = (blockIdx.x >> 3) & 3, kg = blockIdx.x >> 5;
  const int tx = threadIdx.x & 63, ty = threadIdx.x >> 6;
  const int kbase = kg*64;
  for (int cl = ty; cl < 64; cl += 4){
    const int c = cg*64 + cl;
    const int gcol = (c >> 6)*512 + sub*64 + (c & 63);
    tile[cl][tx] = Whh[(size_t)gcol*512 + kbase + tx];
  }
  __syncthreads();
  for (int kk = ty; kk < 64; kk += 4)
    Wpackh[((size_t)sub*512 + kbase + kk)*256 + cg*64 + tx] = tile[tx][kk];
}

// ---------------------------------------------------------------------------
// m97-style bf16 GEMM: C = sum_passes A_p (MxK) * B_p(NxK)^T [+bias]
__global__ __launch_bounds__(256) void gemm_bt_kernel(
    const unsigned short* __restrict__ A0, const unsigned short* __restrict__ A1,
    const unsigned short* __restrict__ A2,
    const unsigned short* __restrict__ B0, const unsigned short* __restrict__ B1,
    const unsigned short* __restrict__ B2,
    float* __restrict__ Cc, const float* __restrict__ bias,
    int N, int K, int npasses, int mt, int swz)
{
  __shared__ __align__(16) unsigned short Al[128*32];
  __shared__ __align__(16) unsigned short Bl[128*32];
  const int tid = threadIdx.x;
  const int wid = tid >> 6, l = tid & 63;
  int f = blockIdx.x;
  if (swz) f = (f & 7)*((int)gridDim.x >> 3) + (f >> 3);
  const int m0 = (f % mt)*128, n0 = (f / mt)*128;
  const int wr = wid >> 1, wc = wid & 1;

  f4v acc[4][4];
  #pragma unroll
  for (int i = 0; i < 4; ++i)
    #pragma unroll
    for (int j = 0; j < 4; ++j) acc[i][j] = (f4v){0.f,0.f,0.f,0.f};

  const int s0 = tid, s1 = tid + 256;
  const int r0 = s0 >> 2, g0 = (s0 & 3) ^ ((r0 >> 1) & 3);
  const int r1 = s1 >> 2, g1 = (s1 & 3) ^ ((r1 >> 1) & 3);
  const int la = l & 15, ch = l >> 4;

  for (int pass = 0; pass < npasses; ++pass){
    const unsigned short* Ap = pass == 0 ? A0 : (pass == 1 ? A1 : A2);
    const unsigned short* Bp = pass == 0 ? B0 : (pass == 1 ? B1 : B2);
    for (int k0 = 0; k0 < K; k0 += 32){
      __syncthreads();
      load_lds16(Ap + (size_t)(m0 + r0)*K + k0 + g0*8, Al + s0*8);
      load_lds16(Ap + (size_t)(m0 + r1)*K + k0 + g1*8, Al + s1*8);
      load_lds16(Bp + (size_t)(n0 + r0)*K + k0 + g0*8, Bl + s0*8);
      load_lds16(Bp + (size_t)(n0 + r1)*K + k0 + g1*8, Bl + s1*8);
      __syncthreads();
      s8v av[4], bv[4];
      #pragma unroll
      for (int mi = 0; mi < 4; ++mi){
        int row = wr*64 + mi*16 + la;
        int cs = ch ^ ((row >> 1) & 3);
        av[mi] = *(const s8v*)(Al + (row*4 + cs)*8);
      }
      #pragma unroll
      for (int ni = 0; ni < 4; ++ni){
        int row = wc*64 + ni*16 + la;
        int cs = ch ^ ((row >> 1) & 3);
        bv[ni] = *(const s8v*)(Bl + (row*4 + cs)*8);
      }
      #pragma unroll
      for (int mi = 0; mi < 4; ++mi)
        #pragma unroll
        for (int ni = 0; ni < 4; ++ni)
          acc[mi][ni] = __builtin_amdgcn_mfma_f32_16x16x32_bf16(av[mi], bv[ni], acc[mi][ni], 0, 0, 0);
    }
  }
  #pragma unroll
  for (int mi = 0; mi < 4; ++mi){
    int row = m0 + wr*64 + mi*16 + (l >> 4)*4;
    #pragma unroll
    for (int ni = 0; ni < 4; ++ni){
      int col = n0 + wc*64 + ni*16 + (l & 15);
      float bb = bias ? bias[col] : 0.0f;
      #pragma unroll
      for (int r = 0; r < 4; ++r)
        Cc[(size_t)(row + r)*N + col] = acc[mi][ni][r] + bb;
    }
  }
}

// ---------------------------------------------------------------------------
// Persistent loop kernel, batch-local groups, zero global sync, 2 minis/step.
// blk = b*8 + sub. Block owns j-slice sub*64..+64 x 4 gates of ITS batch.
// FW tile [196][256]: rows {0..71, 98..169} in LDS f32 (147KB, conflict-free
// stride-1 reads); rows {72..97, 170..195} streamed (0.85MB/XCD, L2-resident).
// Per step: [ge pf] A,B | arrive1 | D-h | wait1 | softmax | D-ctx | update |
//           arrive3 | hall stores | wait3.
__global__ __launch_bounds__(512, 1) void loop_kernel(
    const float* __restrict__ feat_proj,
    const float* __restrict__ WhT, const float* __restrict__ attn_b,
    const float* __restrict__ v_w, const float* __restrict__ Wpackh,
    const float* __restrict__ FW, const float* __restrict__ gates_emb,
    const float* __restrict__ b_ih, const float* __restrict__ b_hh,
    float* __restrict__ hgrp,          // [T+1][B][512]
    const float* __restrict__ c_init,
    float* __restrict__ sps,           // [T][B][200][8]
    unsigned short* __restrict__ hall_h, unsigned short* __restrict__ hall_l,
    unsigned* __restrict__ fm1, unsigned* __restrict__ fm3)
{
  __shared__ float fwl[144*256];   // 147.4KB FW rows (72 per kh-half)
  __shared__ float hs[512];
  __shared__ float hwl[64];
  __shared__ float partA[8][72];
  __shared__ float aux[256];
  __shared__ float biasl[256];
  __shared__ float red[512];
  __shared__ float smx, sinv;

  const int blk = blockIdx.x, tid = threadIdx.x;
  const int b = blk >> 3, sub = blk & 7;
  const int gbase = blk & ~7;
  const int l = tid & 63, wv = tid >> 6;

  // ---- prologue ----
  float wreg[64];
  #pragma unroll
  for (int kk = 0; kk < 64; ++kk)
    wreg[kk] = WhT[(size_t)(wv*64 + kk)*512 + sub*64 + l];
  float fpreg[25];
  #pragma unroll
  for (int i = 0; i < 25; ++i){
    const int p = wv + i*8;
    fpreg[i] = (p < P) ? feat_proj[((size_t)b*P + p)*512 + sub*64 + l] : 0.f;
  }
  for (int c = tid; c < 256; c += NT){
    const int gcol = (c >> 6)*512 + sub*64 + (c & 63);
    biasl[c] = b_ih[gcol] + b_hh[gcol];
  }
  // FW rows -> LDS: row r<72 -> p=r (kh=0 half); r>=72 -> p=26+r (kh=1 half)
  for (int idx = tid; idx < 144*256; idx += NT){
    const int r = idx >> 8, c = idx & 255;
    const int p = (r < 72) ? r : (26 + r);
    const int gc = (c >> 6)*512 + sub*64 + (c & 63);
    fwl[idx] = FW[((size_t)b*P + p)*2048 + gc];
  }
  const float vl = v_w[sub*64 + l];
  const float ab = (tid < 64) ? attn_b[sub*64 + tid] : 0.f;
  float c_reg = 0.f;
  if (tid < 64) c_reg = c_init[b*512 + sub*64 + tid];

  // phase-D decomposition: thread = (dc: block-local col, kh: half)
  const int dc = tid & 255;
  const int kh = tid >> 8;
  const int gcol_d = (dc >> 6)*512 + sub*64 + (dc & 63);
  const float* wp_h = Wpackh + ((size_t)sub*512 + kh*256)*256 + dc;
  const float* fw_st = FW + ((size_t)b*P + kh*98 + 72)*2048 + gcol_d;  // 26 streamed rows
  __syncthreads();

  for (int t = 0; t < T; ++t){
    const unsigned gen = (unsigned)(t + 1);

    // ---- gates_emb prefetch (hidden under A/B/D-h) ----
    float gepre[4];
    if (tid < 64){
      const float* ge = gates_emb + ((size_t)b*T + t)*2048;
      #pragma unroll
      for (int g = 0; g < 4; ++g) gepre[g] = ge[g*512 + sub*64 + tid];
    }

    // ---- A: hWh[b][sub*64..+64) (register WhT slice x LDS-broadcast h) ----
    hs[tid] = hgrp[((size_t)t*B + b)*512 + tid];      // plain (time-indexed)
    __syncthreads();
    {
      const float* hk = hs + wv*64;
      float a = 0.f;
      #pragma unroll
      for (int kk = 0; kk < 64; ++kk) a += hk[kk] * wreg[kk];
      partA[wv][l] = a;
    }
    __syncthreads();
    if (tid < 64){
      float s = ab;
      #pragma unroll
      for (int k = 0; k < 8; ++k) s += partA[k][tid];
      hwl[tid] = s;
    }
    __syncthreads();

    // ---- B: partial scores over own j-slice (feat_proj from registers) ----
    {
      const float hj = hwl[l];
      float* spw = sps + (size_t)(t*B + b)*1600 + sub;
      #pragma unroll
      for (int i = 0; i < 25; ++i){
        const int p = wv + i*8;
        if (p >= P) break;
        float e2 = vl * fast_tanh(fpreg[i] + hj);
        #pragma unroll
        for (int off = 32; off; off >>= 1) e2 += __shfl_xor(e2, off);
        if (l == 0) cohstore(spw + p*8, e2);
      }
    }
    bar_arrive(fm1 + blk, gen);

    // ---- D-h: Whh-part dots (needs only hs; hides mini1 window) ----
    float acch0 = 0.f, acch1 = 0.f, acch2 = 0.f, acch3 = 0.f;
    {
      const float* hk = hs + kh*256;
      #pragma unroll 8
      for (int k = 0; k < 256; k += 4){
        acch0 += wp_h[(size_t)(k+0)*256] * hk[k+0];
        acch1 += wp_h[(size_t)(k+1)*256] * hk[k+1];
        acch2 += wp_h[(size_t)(k+2)*256] * hk[k+2];
        acch3 += wp_h[(size_t)(k+3)*256] * hk[k+3];
      }
    }
    bar_wait(fm1 + gbase, gen);

    // ---- softmax (redundant x8, all operands local/plain) ----
    {
      float sc_v = -1e30f;
      if (tid < P){
        const float* sp = sps + (size_t)(t*B + b)*1600 + tid*8;
        float4 q0 = *(const float4*)sp, q1 = *(const float4*)(sp + 4);
        sc_v = (q0.x + q0.y + q0.z + q0.w) + (q1.x + q1.y + q1.z + q1.w);
      }
      if (tid < 256) aux[tid] = sc_v;
      __syncthreads();
      if (tid < 64){
        float m = -1e30f;
        #pragma unroll
        for (int i = 0; i < 4; ++i) m = fmaxf(m, aux[tid + i*64]);
        #pragma unroll
        for (int off = 32; off; off >>= 1) m = fmaxf(m, __shfl_xor(m, off));
        if (tid == 0) smx = m;
      }
      __syncthreads();
      float al = (tid < P) ? __expf(sc_v - smx) : 0.f;
      if (tid < 256) aux[tid] = al;
      __syncthreads();
      if (tid < 64){
        float s = 0.f;
        #pragma unroll
        for (int i = 0; i < 4; ++i) s += aux[tid + i*64];
        #pragma unroll
        for (int off = 32; off; off >>= 1) s += __shfl_xor(s, off);
        if (tid == 0) sinv = 1.0f/s;
      }
      __syncthreads();
    }

    // ---- D-ctx: rank-P contraction (72 LDS rows + 26 L2-resident rows) ----
    float accc = 0.f;
    {
      const float* ax = aux + kh*98;
      const float* fl = fwl + (size_t)(kh*72)*256 + dc;
      #pragma unroll 8
      for (int lp = 0; lp < 72; ++lp)
        accc += ax[lp] * fl[(size_t)lp*256];
      #pragma unroll
      for (int i = 0; i < 26; ++i)
        accc += ax[72 + i] * fw_st[(size_t)i*2048];
    }
    red[dc*2 + kh] = ((acch0 + acch1) + (acch2 + acch3)) + accc*sinv;
    __syncthreads();

    // ---- LSTM update ----
    if (tid < 64){
      float gv[4];
      #pragma unroll
      for (int g = 0; g < 4; ++g){
        const int c = g*64 + tid;
        gv[g] = red[c*2] + red[c*2 + 1] + biasl[c] + gepre[g];
      }
      const float i_ = sigmoidf_(gv[0]);
      const float f_ = sigmoidf_(gv[1]);
      const float g_ = fast_tanh(gv[2]);
      const float o_ = sigmoidf_(gv[3]);
      const int j = sub*64 + tid;
      const float c_new = f_*c_reg + i_*g_;
      const float h_new = o_*fast_tanh(c_new);
      c_reg = c_new;
      cohstore(hgrp + ((size_t)(t+1)*B + b)*512 + j, h_new);
      const unsigned short hh = f_to_bf16(h_new);
      aux[tid] = __uint_as_float(((unsigned)hh << 16) |
                 (unsigned)f_to_bf16(h_new - bf16_to_f(hh)));
    }
    bar_arrive(fm3 + blk, gen);
    if (tid < 64){
      const unsigned pk = __float_as_uint(aux[tid]);
      const int j = sub*64 + tid;
      hall_h[((size_t)b*T + t)*512 + j] = (unsigned short)(pk >> 16);
      hall_l[((size_t)b*T + t)*512 + j] = (unsigned short)(pk & 0xffffu);
    }
    bar_wait(fm3 + gbase, gen);
  }
}

// ---------------------------------------------------------------------------
extern "C" void kernel_launch(void* const* d_in, const int* in_sizes, int n_in,
                              void* d_out, int out_size, void* d_ws, size_t ws_size,
                              hipStream_t stream)
{
  (void)in_sizes; (void)n_in; (void)out_size;
  const float* features = (const float*)d_in[0];
  const int*   captions = (const int*)d_in[1];
  const float* embed_W  = (const float*)d_in[2];
  const float* attn_W   = (const float*)d_in[3];
  const float* attn_b   = (const float*)d_in[4];
  const float* v_w      = (const float*)d_in[5];
  const float* W_ih     = (const float*)d_in[6];
  const float* W_hh     = (const float*)d_in[7];
  const float* b_ih     = (const float*)d_in[8];
  const float* b_hh     = (const float*)d_in[9];
  const float* lin_W    = (const float*)d_in[10];
  const float* lin_b    = (const float*)d_in[11];
  const float* inith_W  = (const float*)d_in[12];
  const float* inith_b  = (const float*)d_in[13];
  const float* initc_W  = (const float*)d_in[14];
  const float* initc_b  = (const float*)d_in[15];

  // "early" scratch in d_out (~101MB; all dead before final logits GEMM)
  char* o = (char*)d_out;
  unsigned short* feat_hi   = (unsigned short*)o; o += (size_t)(B*P)*E*2;   // 6.4MB
  unsigned short* feat_lo   = (unsigned short*)o; o += (size_t)(B*P)*E*2;   // 6.4MB
  unsigned short* Wf_bf     = (unsigned short*)o; o += (size_t)H*E*2;       // 0.5MB
  float*          feat_proj = (float*)o;          o += (size_t)(B*P)*H*4;   // 12.9MB
  unsigned short* emb_hi    = (unsigned short*)o; o += (size_t)(B*T)*E*2;   // 1.05MB
  unsigned short* emb_lo    = (unsigned short*)o; o += (size_t)(B*T)*E*2;
  unsigned short* Wihe_hi   = (unsigned short*)o; o += (size_t)2048*512*2;  // 2.1MB
  unsigned short* Wihe_lo   = (unsigned short*)o; o += (size_t)2048*512*2;
  unsigned short* Wihc_hi   = (unsigned short*)o; o += (size_t)2048*512*2;  // 2.1MB
  unsigned short* Wihc_lo   = (unsigned short*)o; o += (size_t)2048*512*2;
  float*          gates_emb = (float*)o;          o += (size_t)(B*T)*2048*4;// 8.4MB
  float*          Wpackh    = (float*)o;          o += (size_t)8*512*256*4; // 4.2MB
  float*          FW        = (float*)o;          o += (size_t)(B*P)*2048*4;// 51.4MB

  // persistent scratch in d_ws
  const size_t SZ_LIN  = (size_t)V*H*2;               // 32.77MB
  const size_t SZ_HALL = (size_t)(B*T)*H*2;           // 1MB
  const size_t SZ_HG   = (size_t)(T+1)*B*512*4;       // 2.16MB
  const size_t SZ_SPS  = (size_t)T*B*200*8*4;         // 6.55MB
  const size_t SZ_ST   = (size_t)B*H*4;               // 64KB
  const size_t SZ_WHT  = (size_t)H*H*4;               // 1MB
  const size_t SZ_FLG  = 4096;
  const size_t need_wo = SZ_LIN + 2*SZ_HALL + SZ_HG + SZ_SPS + SZ_ST + SZ_WHT + SZ_FLG;
  const bool three = (ws_size >= need_wo + SZ_LIN);

  char* w = (char*)d_ws;
  unsigned short* lin_hi  = (unsigned short*)w; w += SZ_LIN;
  unsigned short* lin_lo  = (unsigned short*)w; if (three) w += SZ_LIN;
  unsigned short* hall_hi = (unsigned short*)w; w += SZ_HALL;
  unsigned short* hall_lo = (unsigned short*)w; w += SZ_HALL;
  float*          hgrp    = (float*)w;          w += SZ_HG;
  float*          sps     = (float*)w;          w += SZ_SPS;
  float*          c_state = (float*)w;          w += SZ_ST;
  float*          WhT_ws  = (float*)w;          w += SZ_WHT;
  unsigned*       flags   = (unsigned*)w;       w += SZ_FLG;
  unsigned* fm1 = flags;           // [256]
  unsigned* fm3 = flags + 256;     // [256]

  // --- conversions / gathers / packs / init ---
  split_kernel<<<2048, 256, 0, stream>>>(features, E, 0, B*P, feat_hi, feat_lo, E, 0);
  split_kernel<<<256, 256, 0, stream>>>(attn_W, E+H, 0, H, Wf_bf, nullptr, E, 0);
  split_kernel<<<2048, 256, 0, stream>>>(lin_W, 512, 0, V, lin_hi, three ? lin_lo : nullptr, 512, 0);
  split_kernel<<<1024, 256, 0, stream>>>(W_ih, 1024, 0, 2048, Wihe_hi, Wihe_lo, 512, 0);
  split_kernel<<<1024, 256, 0, stream>>>(W_ih, 1024, 512, 2048, Wihc_hi, Wihc_lo, 512, 0);
  embed_kernel<<<B*T, 256, 0, stream>>>(captions, embed_W, emb_hi, emb_lo);
  prep_kernel<<<B, 512, 0, stream>>>(features, inith_W, inith_b, initc_W, initc_b,
                                     hgrp, c_state);
  transpose_wh_kernel<<<64, 256, 0, stream>>>(attn_W, WhT_ws);
  pack_whh_kernel<<<256, 256, 0, stream>>>(W_hh, Wpackh);
  hipMemsetAsync(flags, 0, SZ_FLG, stream);

  // feat_proj = features @ Wf^T (bf16 1-pass; error damped through tanh/softmax)
  gemm_bt_kernel<<<(B*P/128)*(E/128), 256, 0, stream>>>(
      feat_hi, feat_hi, feat_hi, Wf_bf, Wf_bf, Wf_bf,
      feat_proj, nullptr, E, E, 1, B*P/128, 0);
  // gates_emb = emb @ W_ih[:, :512]^T (bf16x3)
  gemm_bt_kernel<<<(B*T/128)*(2048/128), 256, 0, stream>>>(
      emb_hi, emb_lo, emb_hi, Wihe_hi, Wihe_hi, Wihe_lo,
      gates_emb, nullptr, 2048, 512, 3, B*T/128, 1);
  // FW = features @ W_ih[:, 512:]^T (bf16x3) — the ctx-gate precompute
  gemm_bt_kernel<<<(B*P/128)*(2048/128), 256, 0, stream>>>(
      feat_hi, feat_lo, feat_hi, Wihc_hi, Wihc_hi, Wihc_lo,
      FW, nullptr, 2048, 512, 3, B*P/128, 1);

  // --- recurrence: one persistent kernel, zero global sync, 2 minis/step ---
  loop_kernel<<<NB, NT, 0, stream>>>(
      feat_proj, WhT_ws, attn_b, v_w, Wpackh, FW, gates_emb, b_ih, b_hh,
      hgrp, c_state, sps, hall_hi, hall_lo, fm1, fm3);

  // --- logits = h_all @ lin_W^T + lin_b (bf16x3, XCD-swizzled grid) ---
  gemm_bt_kernel<<<(V/128)*(B*T/128), 256, 0, stream>>>(
      hall_hi, hall_lo, hall_hi, lin_hi, lin_hi, three ? lin_lo : lin_hi,
      (float*)d_out, lin_b, V, H, three ? 3 : 2, B*T/128, 1);
}

// Round 21
// 1029.287 us; speedup vs baseline: 1.1949x; 1.1084x over previous
//
// CaptionDecoder on MI355X — round 21: r18 loop + XCD-LOCAL groups + bf16 Wpackh.
// r20 lesson: FW streaming (r18) is hidden under the barrier window — keep it.
// r12-r20 mapping bug: blk=b*8+sub puts the 8 group members on 8 DIFFERENT
// XCDs (consecutive ids round-robin) -> every mini is cross-XCD. Fix:
// blk=sub*32+b -> all group members on ONE XCD. Wpackh -> bf16 so all 8
// slices (2.1MB) fit each XCD's L2.
#include <hip/hip_runtime.h>

#define E 512
#define H 512
#define V 32000
#define B 32
#define P 196
#define T 32
#define NB 256
#define NT 512

typedef __attribute__((ext_vector_type(8))) short s8v;    // 8 bf16
typedef __attribute__((ext_vector_type(4))) float f4v;    // 4 f32 acc

__device__ __forceinline__ float bf16_to_f(unsigned short u){
  return __uint_as_float(((unsigned)u) << 16);
}
__device__ __forceinline__ unsigned short f_to_bf16(float f){
  unsigned u = __float_as_uint(f);
  u += 0x7FFFu + ((u >> 16) & 1u);   // RNE
  return (unsigned short)(u >> 16);
}
__device__ __forceinline__ float fast_tanh(float x){
  float e = __expf(2.0f*x);
  return 1.0f - 2.0f/(e + 1.0f);
}
__device__ __forceinline__ float sigmoidf_(float x){
  return 1.0f/(1.0f + __expf(-x));
}
__device__ __forceinline__ void load_lds16(const unsigned short* g, unsigned short* l){
  __builtin_amdgcn_global_load_lds(
      (const __attribute__((address_space(1))) void*)g,
      (__attribute__((address_space(3))) void*)l, 16, 0, 0);
}
__device__ __forceinline__ float dot4(float4 a, float4 b){
  return a.x*b.x + a.y*b.y + a.z*b.z + a.w*b.w;
}

#define AT_SCOPE __HIP_MEMORY_SCOPE_AGENT
__device__ __forceinline__ void cohstore(float* p, float v){
  __hip_atomic_store(p, v, __ATOMIC_RELAXED, AT_SCOPE);
}
__device__ __forceinline__ unsigned cohldu(const unsigned* p){
  return __hip_atomic_load(p, __ATOMIC_RELAXED, AT_SCOPE);
}
__device__ __forceinline__ void cohstu(unsigned* p, unsigned v){
  __hip_atomic_store(p, v, __ATOMIC_RELAXED, AT_SCOPE);
}

// 8-block mini-barrier, split arrive/wait (all relaxed; __syncthreads drains
// vmcnt -> block's coherent stores are LLC-visible before the flag publish).
__device__ __forceinline__ void bar_arrive(unsigned* my, unsigned gen){
  __syncthreads();
  if (threadIdx.x == 0) cohstu(my, gen);
}
__device__ __forceinline__ void bar_wait(const unsigned* base, unsigned gen){
  if (threadIdx.x < 64){
    for (;;){
      unsigned mn = 0xffffffffu;
      for (int i = (int)threadIdx.x; i < 8; i += 64){
        unsigned v = cohldu(base + i);
        mn = v < mn ? v : mn;
      }
      #pragma unroll
      for (int off = 32; off; off >>= 1){
        unsigned o2 = (unsigned)__shfl_xor((int)mn, off);
        mn = o2 < mn ? o2 : mn;
      }
      if (mn >= gen) break;
      __builtin_amdgcn_s_sleep(1);
    }
    __builtin_amdgcn_sched_barrier(0);
  }
  __syncthreads();
}

// ---------------------------------------------------------------------------
// f32 (strided) -> bf16 hi (+ optional lo residual). cols==512.
__global__ void split_kernel(const float* __restrict__ src, int src_ld, int src_coff,
                             int rows,
                             unsigned short* __restrict__ dhi, unsigned short* __restrict__ dlo,
                             int dst_ld, int dst_coff)
{
  int n = rows << 9;
  for (int i = blockIdx.x*blockDim.x + threadIdx.x; i < n; i += gridDim.x*blockDim.x){
    int r = i >> 9, c = i & 511;
    float x = src[(size_t)r*src_ld + src_coff + c];
    unsigned short h = f_to_bf16(x);
    dhi[(size_t)r*dst_ld + dst_coff + c] = h;
    if (dlo) dlo[(size_t)r*dst_ld + dst_coff + c] = f_to_bf16(x - bf16_to_f(h));
  }
}

// Embedding gather -> bf16 hi/lo rows (row = b*T + t)
__global__ void embed_kernel(const int* __restrict__ caps, const float* __restrict__ embW,
                             unsigned short* __restrict__ ehi, unsigned short* __restrict__ elo)
{
  int row = blockIdx.x;
  int cap = caps[row];
  const float* s = embW + (size_t)cap*E;
  for (int e = threadIdx.x; e < E; e += blockDim.x){
    float x = s[e];
    unsigned short h = f_to_bf16(x);
    ehi[(size_t)row*E + e] = h;
    elo[(size_t)row*E + e] = f_to_bf16(x - bf16_to_f(h));
  }
}

// mean over P, then h0 -> hgrp[0][b], c0 -> c_state
__global__ __launch_bounds__(512) void prep_kernel(
    const float* __restrict__ feats,
    const float* __restrict__ inith_W, const float* __restrict__ inith_b,
    const float* __restrict__ initc_W, const float* __restrict__ initc_b,
    float* __restrict__ hgrp, float* __restrict__ c_state)
{
  __shared__ float mf[E];
  const int b = blockIdx.x, tid = threadIdx.x;
  const float* fb = feats + (size_t)b*P*E + tid;
  float s = 0.f;
  for (int p = 0; p < P; ++p) s += fb[(size_t)p*E];
  mf[tid] = s * (1.0f/196.0f);
  __syncthreads();
  const float* wh = inith_W + (size_t)tid*E;
  const float* wc = initc_W + (size_t)tid*E;
  float h0 = inith_b[tid], c0 = initc_b[tid];
  #pragma unroll 4
  for (int e = 0; e < E; e += 4){
    float4 a4 = *(const float4*)(wh + e);
    float4 b4 = *(const float4*)(wc + e);
    float4 m4 = *(const float4*)(mf + e);
    h0 += dot4(a4, m4);
    c0 += dot4(b4, m4);
  }
  hgrp[(size_t)b*512 + tid] = h0;
  c_state[b*512 + tid] = c0;
}

// WhT[k][j] = attn_W[j][E + k]
__global__ __launch_bounds__(256) void transpose_wh_kernel(
    const float* __restrict__ attn_W, float* __restrict__ WhT)
{
  __shared__ float tile[64][65];
  const int jt = blockIdx.x & 7, kt = blockIdx.x >> 3;
  const int tx = threadIdx.x & 63, ty = threadIdx.x >> 6;
  for (int r = ty; r < 64; r += 4)
    tile[r][tx] = attn_W[(size_t)(jt*64 + r)*(E+H) + E + kt*64 + tx];
  __syncthreads();
  for (int r = ty; r < 64; r += 4)
    WhT[(size_t)(kt*64 + r)*512 + jt*64 + tx] = tile[tx][r];
}

// Wpackh[sub][k][c] in BF16: k in [0,512) = Whh row of gate col; c in [0,256):
// gcol = (c>>6)*512 + sub*64 + (c&63). Coalesced repack. (bf16 error in the
// Whh*h gate term ~1e-5 — negligible vs the 8.3e-4 budget.)
__global__ __launch_bounds__(256) void pack_whh_kernel(
    const float* __restrict__ Whh, unsigned short* __restrict__ Wpackh)
{
  __shared__ float tile[64][65];
  const int sub = blockIdx.x & 7, cg = (blockIdx.x >> 3) & 3, kg = blockIdx.x >> 5;
  const int tx = threadIdx.x & 63, ty = threadIdx.x >> 6;
  const int kbase = kg*64;
  for (int cl = ty; cl < 64; cl += 4){
    const int c = cg*64 + cl;
    const int gcol = (c >> 6)*512 + sub*64 + (c & 63);
    tile[cl][tx] = Whh[(size_t)gcol*512 + kbase + tx];
  }
  __syncthreads();
  for (int kk = ty; kk < 64; kk += 4)
    Wpackh[((size_t)sub*512 + kbase + kk)*256 + cg*64 + tx] = f_to_bf16(tile[tx][kk]);
}

// ---------------------------------------------------------------------------
// m97-style bf16 GEMM: C = sum_passes A_p (MxK) * B_p(NxK)^T [+bias]
__global__ __launch_bounds__(256) void gemm_bt_kernel(
    const unsigned short* __restrict__ A0, const unsigned short* __restrict__ A1,
    const unsigned short* __restrict__ A2,
    const unsigned short* __restrict__ B0, const unsigned short* __restrict__ B1,
    const unsigned short* __restrict__ B2,
    float* __restrict__ Cc, const float* __restrict__ bias,
    int N, int K, int npasses, int mt, int swz)
{
  __shared__ __align__(16) unsigned short Al[128*32];
  __shared__ __align__(16) unsigned short Bl[128*32];
  const int tid = threadIdx.x;
  const int wid = tid >> 6, l = tid & 63;
  int f = blockIdx.x;
  if (swz) f = (f & 7)*((int)gridDim.x >> 3) + (f >> 3);
  const int m0 = (f % mt)*128, n0 = (f / mt)*128;
  const int wr = wid >> 1, wc = wid & 1;

  f4v acc[4][4];
  #pragma unroll
  for (int i = 0; i < 4; ++i)
    #pragma unroll
    for (int j = 0; j < 4; ++j) acc[i][j] = (f4v){0.f,0.f,0.f,0.f};

  const int s0 = tid, s1 = tid + 256;
  const int r0 = s0 >> 2, g0 = (s0 & 3) ^ ((r0 >> 1) & 3);
  const int r1 = s1 >> 2, g1 = (s1 & 3) ^ ((r1 >> 1) & 3);
  const int la = l & 15, ch = l >> 4;

  for (int pass = 0; pass < npasses; ++pass){
    const unsigned short* Ap = pass == 0 ? A0 : (pass == 1 ? A1 : A2);
    const unsigned short* Bp = pass == 0 ? B0 : (pass == 1 ? B1 : B2);
    for (int k0 = 0; k0 < K; k0 += 32){
      __syncthreads();
      load_lds16(Ap + (size_t)(m0 + r0)*K + k0 + g0*8, Al + s0*8);
      load_lds16(Ap + (size_t)(m0 + r1)*K + k0 + g1*8, Al + s1*8);
      load_lds16(Bp + (size_t)(n0 + r0)*K + k0 + g0*8, Bl + s0*8);
      load_lds16(Bp + (size_t)(n0 + r1)*K + k0 + g1*8, Bl + s1*8);
      __syncthreads();
      s8v av[4], bv[4];
      #pragma unroll
      for (int mi = 0; mi < 4; ++mi){
        int row = wr*64 + mi*16 + la;
        int cs = ch ^ ((row >> 1) & 3);
        av[mi] = *(const s8v*)(Al + (row*4 + cs)*8);
      }
      #pragma unroll
      for (int ni = 0; ni < 4; ++ni){
        int row = wc*64 + ni*16 + la;
        int cs = ch ^ ((row >> 1) & 3);
        bv[ni] = *(const s8v*)(Bl + (row*4 + cs)*8);
      }
      #pragma unroll
      for (int mi = 0; mi < 4; ++mi)
        #pragma unroll
        for (int ni = 0; ni < 4; ++ni)
          acc[mi][ni] = __builtin_amdgcn_mfma_f32_16x16x32_bf16(av[mi], bv[ni], acc[mi][ni], 0, 0, 0);
    }
  }
  #pragma unroll
  for (int mi = 0; mi < 4; ++mi){
    int row = m0 + wr*64 + mi*16 + (l >> 4)*4;
    #pragma unroll
    for (int ni = 0; ni < 4; ++ni){
      int col = n0 + wc*64 + ni*16 + (l & 15);
      float bb = bias ? bias[col] : 0.0f;
      #pragma unroll
      for (int r = 0; r < 4; ++r)
        Cc[(size_t)(row + r)*N + col] = acc[mi][ni][r] + bb;
    }
  }
}

// ---------------------------------------------------------------------------
// Persistent loop kernel, batch-local groups, zero global sync, 2 minis/step.
// blk = sub*32 + b  =>  all 8 group members (subs of batch b) share blk%8 =
// b%8 = ONE XCD: minis and sps/h exchange are XCD-local. Block owns j-slice
// sub*64..+64 x 4 gates of ITS batch. FW streamed (hidden under barriers).
// Per step: [ge pf] A,B | arrive1 | D-h | wait1 | softmax | D-ctx | update |
//           arrive3 | hall stores | wait3.
__global__ __launch_bounds__(512, 1) void loop_kernel(
    const float* __restrict__ feat_proj,
    const float* __restrict__ WhT, const float* __restrict__ attn_b,
    const float* __restrict__ v_w, const unsigned short* __restrict__ Wpackh,
    const float* __restrict__ FW, const float* __restrict__ gates_emb,
    const float* __restrict__ b_ih, const float* __restrict__ b_hh,
    float* __restrict__ hgrp,          // [T+1][B][512]
    const float* __restrict__ c_init,
    float* __restrict__ sps,           // [T][B][200][8]
    unsigned short* __restrict__ hall_h, unsigned short* __restrict__ hall_l,
    unsigned* __restrict__ fm1, unsigned* __restrict__ fm3)
{
  __shared__ float hs[512];
  __shared__ float hwl[64];
  __shared__ float partA[8][72];
  __shared__ float aux[256];
  __shared__ float biasl[256];
  __shared__ float red[512];
  __shared__ float smx, sinv;

  const int blk = blockIdx.x, tid = threadIdx.x;
  const int b = blk & 31, sub = blk >> 5;       // XCD-local group mapping
  const int l = tid & 63, wv = tid >> 6;

  // ---- prologue ----
  float wreg[64];
  #pragma unroll
  for (int kk = 0; kk < 64; ++kk)
    wreg[kk] = WhT[(size_t)(wv*64 + kk)*512 + sub*64 + l];
  float fpreg[25];
  #pragma unroll
  for (int i = 0; i < 25; ++i){
    const int p = wv + i*8;
    fpreg[i] = (p < P) ? feat_proj[((size_t)b*P + p)*512 + sub*64 + l] : 0.f;
  }
  for (int c = tid; c < 256; c += NT){
    const int gcol = (c >> 6)*512 + sub*64 + (c & 63);
    biasl[c] = b_ih[gcol] + b_hh[gcol];
  }
  const float vl = v_w[sub*64 + l];
  const float ab = (tid < 64) ? attn_b[sub*64 + tid] : 0.f;
  float c_reg = 0.f;
  if (tid < 64) c_reg = c_init[b*512 + sub*64 + tid];

  // phase-D decomposition: thread = (dc: block-local col, kh: half)
  const int dc = tid & 255;
  const int kh = tid >> 8;
  const int gcol_d = (dc >> 6)*512 + sub*64 + (dc & 63);
  const unsigned short* wp_h = Wpackh + ((size_t)sub*512 + kh*256)*256 + dc;
  const float* fw_th = FW + ((size_t)b*P + kh*98)*2048 + gcol_d;
  __syncthreads();

  for (int t = 0; t < T; ++t){
    const unsigned gen = (unsigned)(t + 1);

    // ---- gates_emb prefetch (hidden under A/B/D-h) ----
    float gepre[4];
    if (tid < 64){
      const float* ge = gates_emb + ((size_t)b*T + t)*2048;
      #pragma unroll
      for (int g = 0; g < 4; ++g) gepre[g] = ge[g*512 + sub*64 + tid];
    }

    // ---- A: hWh[b][sub*64..+64) (register WhT slice x LDS-broadcast h) ----
    hs[tid] = hgrp[((size_t)t*B + b)*512 + tid];      // plain (time-indexed)
    __syncthreads();
    {
      const float* hk = hs + wv*64;
      float a = 0.f;
      #pragma unroll
      for (int kk = 0; kk < 64; ++kk) a += hk[kk] * wreg[kk];
      partA[wv][l] = a;
    }
    __syncthreads();
    if (tid < 64){
      float s = ab;
      #pragma unroll
      for (int k = 0; k < 8; ++k) s += partA[k][tid];
      hwl[tid] = s;
    }
    __syncthreads();

    // ---- B: partial scores over own j-slice (feat_proj from registers) ----
    {
      const float hj = hwl[l];
      float* spw = sps + (size_t)(t*B + b)*1600 + sub;
      #pragma unroll
      for (int i = 0; i < 25; ++i){
        const int p = wv + i*8;
        if (p >= P) break;
        float e2 = vl * fast_tanh(fpreg[i] + hj);
        #pragma unroll
        for (int off = 32; off; off >>= 1) e2 += __shfl_xor(e2, off);
        if (l == 0) cohstore(spw + p*8, e2);
      }
    }
    bar_arrive(fm1 + b*8 + sub, gen);

    // ---- D-h: Whh(bf16)-part dots (needs only hs; hides mini1 window) ----
    float acch0 = 0.f, acch1 = 0.f, acch2 = 0.f, acch3 = 0.f;
    {
      const float* hk = hs + kh*256;
      #pragma unroll 8
      for (int k = 0; k < 256; k += 4){
        acch0 += bf16_to_f(wp_h[(size_t)(k+0)*256]) * hk[k+0];
        acch1 += bf16_to_f(wp_h[(size_t)(k+1)*256]) * hk[k+1];
        acch2 += bf16_to_f(wp_h[(size_t)(k+2)*256]) * hk[k+2];
        acch3 += bf16_to_f(wp_h[(size_t)(k+3)*256]) * hk[k+3];
      }
    }
    bar_wait(fm1 + b*8, gen);

    // ---- softmax (redundant x8, all operands local/plain) ----
    {
      float sc_v = -1e30f;
      if (tid < P){
        const float* sp = sps + (size_t)(t*B + b)*1600 + tid*8;
        float4 q0 = *(const float4*)sp, q1 = *(const float4*)(sp + 4);
        sc_v = (q0.x + q0.y + q0.z + q0.w) + (q1.x + q1.y + q1.z + q1.w);
      }
      if (tid < 256) aux[tid] = sc_v;
      __syncthreads();
      if (tid < 64){
        float m = -1e30f;
        #pragma unroll
        for (int i = 0; i < 4; ++i) m = fmaxf(m, aux[tid + i*64]);
        #pragma unroll
        for (int off = 32; off; off >>= 1) m = fmaxf(m, __shfl_xor(m, off));
        if (tid == 0) smx = m;
      }
      __syncthreads();
      float al = (tid < P) ? __expf(sc_v - smx) : 0.f;
      if (tid < 256) aux[tid] = al;
      __syncthreads();
      if (tid < 64){
        float s = 0.f;
        #pragma unroll
        for (int i = 0; i < 4; ++i) s += aux[tid + i*64];
        #pragma unroll
        for (int off = 32; off; off >>= 1) s += __shfl_xor(s, off);
        if (tid == 0) sinv = 1.0f/s;
      }
      __syncthreads();
    }

    // ---- D-ctx: rank-P contraction against streamed FW (L3, hidden) ----
    float accc = 0.f;
    {
      const float* ax = aux + kh*98;
      #pragma unroll 7
      for (int i = 0; i < 98; ++i)
        accc += ax[i] * fw_th[(size_t)i*2048];
    }
    red[dc*2 + kh] = ((acch0 + acch1) + (acch2 + acch3)) + accc*sinv;
    __syncthreads();

    // ---- LSTM update ----
    if (tid < 64){
      float gv[4];
      #pragma unroll
      for (int g = 0; g < 4; ++g){
        const int c = g*64 + tid;
        gv[g] = red[c*2] + red[c*2 + 1] + biasl[c] + gepre[g];
      }
      const float i_ = sigmoidf_(gv[0]);
      const float f_ = sigmoidf_(gv[1]);
      const float g_ = fast_tanh(gv[2]);
      const float o_ = sigmoidf_(gv[3]);
      const int j = sub*64 + tid;
      const float c_new = f_*c_reg + i_*g_;
      const float h_new = o_*fast_tanh(c_new);
      c_reg = c_new;
      cohstore(hgrp + ((size_t)(t+1)*B + b)*512 + j, h_new);
      const unsigned short hh = f_to_bf16(h_new);
      aux[tid] = __uint_as_float(((unsigned)hh << 16) |
                 (unsigned)f_to_bf16(h_new - bf16_to_f(hh)));
    }
    bar_arrive(fm3 + b*8 + sub, gen);
    if (tid < 64){
      const unsigned pk = __float_as_uint(aux[tid]);
      const int j = sub*64 + tid;
      hall_h[((size_t)b*T + t)*512 + j] = (unsigned short)(pk >> 16);
      hall_l[((size_t)b*T + t)*512 + j] = (unsigned short)(pk & 0xffffu);
    }
    bar_wait(fm3 + b*8, gen);
  }
}

// ---------------------------------------------------------------------------
extern "C" void kernel_launch(void* const* d_in, const int* in_sizes, int n_in,
                              void* d_out, int out_size, void* d_ws, size_t ws_size,
                              hipStream_t stream)
{
  (void)in_sizes; (void)n_in; (void)out_size;
  const float* features = (const float*)d_in[0];
  const int*   captions = (const int*)d_in[1];
  const float* embed_W  = (const float*)d_in[2];
  const float* attn_W   = (const float*)d_in[3];
  const float* attn_b   = (const float*)d_in[4];
  const float* v_w      = (const float*)d_in[5];
  const float* W_ih     = (const float*)d_in[6];
  const float* W_hh     = (const float*)d_in[7];
  const float* b_ih     = (const float*)d_in[8];
  const float* b_hh     = (const float*)d_in[9];
  const float* lin_W    = (const float*)d_in[10];
  const float* lin_b    = (const float*)d_in[11];
  const float* inith_W  = (const float*)d_in[12];
  const float* inith_b  = (const float*)d_in[13];
  const float* initc_W  = (const float*)d_in[14];
  const float* initc_b  = (const float*)d_in[15];

  // "early" scratch in d_out (~99MB; all dead before final logits GEMM)
  char* o = (char*)d_out;
  unsigned short* feat_hi   = (unsigned short*)o; o += (size_t)(B*P)*E*2;   // 6.4MB
  unsigned short* feat_lo   = (unsigned short*)o; o += (size_t)(B*P)*E*2;   // 6.4MB
  unsigned short* Wf_bf     = (unsigned short*)o; o += (size_t)H*E*2;       // 0.5MB
  float*          feat_proj = (float*)o;          o += (size_t)(B*P)*H*4;   // 12.9MB
  unsigned short* emb_hi    = (unsigned short*)o; o += (size_t)(B*T)*E*2;   // 1.05MB
  unsigned short* emb_lo    = (unsigned short*)o; o += (size_t)(B*T)*E*2;
  unsigned short* Wihe_hi   = (unsigned short*)o; o += (size_t)2048*512*2;  // 2.1MB
  unsigned short* Wihe_lo   = (unsigned short*)o; o += (size_t)2048*512*2;
  unsigned short* Wihc_hi   = (unsigned short*)o; o += (size_t)2048*512*2;  // 2.1MB
  unsigned short* Wihc_lo   = (unsigned short*)o; o += (size_t)2048*512*2;
  float*          gates_emb = (float*)o;          o += (size_t)(B*T)*2048*4;// 8.4MB
  unsigned short* Wpackh    = (unsigned short*)o; o += (size_t)8*512*256*2; // 2.1MB
  float*          FW        = (float*)o;          o += (size_t)(B*P)*2048*4;// 51.4MB

  // persistent scratch in d_ws
  const size_t SZ_LIN  = (size_t)V*H*2;               // 32.77MB
  const size_t SZ_HALL = (size_t)(B*T)*H*2;           // 1MB
  const size_t SZ_HG   = (size_t)(T+1)*B*512*4;       // 2.16MB
  const size_t SZ_SPS  = (size_t)T*B*200*8*4;         // 6.55MB
  const size_t SZ_ST   = (size_t)B*H*4;               // 64KB
  const size_t SZ_WHT  = (size_t)H*H*4;               // 1MB
  const size_t SZ_FLG  = 4096;
  const size_t need_wo = SZ_LIN + 2*SZ_HALL + SZ_HG + SZ_SPS + SZ_ST + SZ_WHT + SZ_FLG;
  const bool three = (ws_size >= need_wo + SZ_LIN);

  char* w = (char*)d_ws;
  unsigned short* lin_hi  = (unsigned short*)w; w += SZ_LIN;
  unsigned short* lin_lo  = (unsigned short*)w; if (three) w += SZ_LIN;
  unsigned short* hall_hi = (unsigned short*)w; w += SZ_HALL;
  unsigned short* hall_lo = (unsigned short*)w; w += SZ_HALL;
  float*          hgrp    = (float*)w;          w += SZ_HG;
  float*          sps     = (float*)w;          w += SZ_SPS;
  float*          c_state = (float*)w;          w += SZ_ST;
  float*          WhT_ws  = (float*)w;          w += SZ_WHT;
  unsigned*       flags   = (unsigned*)w;       w += SZ_FLG;
  unsigned* fm1 = flags;           // [256] indexed [b*8+sub]
  unsigned* fm3 = flags + 256;     // [256]

  // --- conversions / gathers / packs / init ---
  split_kernel<<<2048, 256, 0, stream>>>(features, E, 0, B*P, feat_hi, feat_lo, E, 0);
  split_kernel<<<256, 256, 0, stream>>>(attn_W, E+H, 0, H, Wf_bf, nullptr, E, 0);
  split_kernel<<<2048, 256, 0, stream>>>(lin_W, 512, 0, V, lin_hi, three ? lin_lo : nullptr, 512, 0);
  split_kernel<<<1024, 256, 0, stream>>>(W_ih, 1024, 0, 2048, Wihe_hi, Wihe_lo, 512, 0);
  split_kernel<<<1024, 256, 0, stream>>>(W_ih, 1024, 512, 2048, Wihc_hi, Wihc_lo, 512, 0);
  embed_kernel<<<B*T, 256, 0, stream>>>(captions, embed_W, emb_hi, emb_lo);
  prep_kernel<<<B, 512, 0, stream>>>(features, inith_W, inith_b, initc_W, initc_b,
                                     hgrp, c_state);
  transpose_wh_kernel<<<64, 256, 0, stream>>>(attn_W, WhT_ws);
  pack_whh_kernel<<<256, 256, 0, stream>>>(W_hh, Wpackh);
  hipMemsetAsync(flags, 0, SZ_FLG, stream);

  // feat_proj = features @ Wf^T (bf16 1-pass; error damped through tanh/softmax)
  gemm_bt_kernel<<<(B*P/128)*(E/128), 256, 0, stream>>>(
      feat_hi, feat_hi, feat_hi, Wf_bf, Wf_bf, Wf_bf,
      feat_proj, nullptr, E, E, 1, B*P/128, 0);
  // gates_emb = emb @ W_ih[:, :512]^T (bf16x3)
  gemm_bt_kernel<<<(B*T/128)*(2048/128), 256, 0, stream>>>(
      emb_hi, emb_lo, emb_hi, Wihe_hi, Wihe_hi, Wihe_lo,
      gates_emb, nullptr, 2048, 512, 3, B*T/128, 1);
  // FW = features @ W_ih[:, 512:]^T (bf16x3) — the ctx-gate precompute
  gemm_bt_kernel<<<(B*P/128)*(2048/128), 256, 0, stream>>>(
      feat_hi, feat_lo, feat_hi, Wihc_hi, Wihc_hi, Wihc_lo,
      FW, nullptr, 2048, 512, 3, B*P/128, 1);

  // --- recurrence: one persistent kernel, zero global sync, 2 minis/step ---
  loop_kernel<<<NB, NT, 0, stream>>>(
      feat_proj, WhT_ws, attn_b, v_w, Wpackh, FW, gates_emb, b_ih, b_hh,
      hgrp, c_state, sps, hall_hi, hall_lo, fm1, fm3);

  // --- logits = h_all @ lin_W^T + lin_b (bf16x3, XCD-swizzled grid) ---
  gemm_bt_kernel<<<(V/128)*(B*T/128), 256, 0, stream>>>(
      hall_hi, hall_lo, hall_hi, lin_hi, lin_hi, three ? lin_lo : lin_hi,
      (float*)d_out, lin_b, V, H, three ? 3 : 2, B*T/128, 1);
}

// Round 22
// 1017.125 us; speedup vs baseline: 1.2092x; 1.0120x over previous
//
// CaptionDecoder on MI355X — round 22: r21 + FW stored in BF16 (halve the stream).
// r21 counters: loop is HBM-bound on the FW stream (1.08GB FETCH, 1.7TB/s).
// FW feeds a softmax-weighted sum (sum alpha = 1): bf16 rounding -> logit
// error ~5e-5, negligible. Stream halves (17MB/step), partially L2-caches.
#include <hip/hip_runtime.h>

#define E 512
#define H 512
#define V 32000
#define B 32
#define P 196
#define T 32
#define NB 256
#define NT 512

typedef __attribute__((ext_vector_type(8))) short s8v;    // 8 bf16
typedef __attribute__((ext_vector_type(4))) float f4v;    // 4 f32 acc

__device__ __forceinline__ float bf16_to_f(unsigned short u){
  return __uint_as_float(((unsigned)u) << 16);
}
__device__ __forceinline__ unsigned short f_to_bf16(float f){
  unsigned u = __float_as_uint(f);
  u += 0x7FFFu + ((u >> 16) & 1u);   // RNE
  return (unsigned short)(u >> 16);
}
__device__ __forceinline__ float fast_tanh(float x){
  float e = __expf(2.0f*x);
  return 1.0f - 2.0f/(e + 1.0f);
}
__device__ __forceinline__ float sigmoidf_(float x){
  return 1.0f/(1.0f + __expf(-x));
}
__device__ __forceinline__ void load_lds16(const unsigned short* g, unsigned short* l){
  __builtin_amdgcn_global_load_lds(
      (const __attribute__((address_space(1))) void*)g,
      (__attribute__((address_space(3))) void*)l, 16, 0, 0);
}
__device__ __forceinline__ float dot4(float4 a, float4 b){
  return a.x*b.x + a.y*b.y + a.z*b.z + a.w*b.w;
}

#define AT_SCOPE __HIP_MEMORY_SCOPE_AGENT
__device__ __forceinline__ void cohstore(float* p, float v){
  __hip_atomic_store(p, v, __ATOMIC_RELAXED, AT_SCOPE);
}
__device__ __forceinline__ unsigned cohldu(const unsigned* p){
  return __hip_atomic_load(p, __ATOMIC_RELAXED, AT_SCOPE);
}
__device__ __forceinline__ void cohstu(unsigned* p, unsigned v){
  __hip_atomic_store(p, v, __ATOMIC_RELAXED, AT_SCOPE);
}

// 8-block mini-barrier, split arrive/wait (all relaxed; __syncthreads drains
// vmcnt -> block's coherent stores are LLC-visible before the flag publish).
__device__ __forceinline__ void bar_arrive(unsigned* my, unsigned gen){
  __syncthreads();
  if (threadIdx.x == 0) cohstu(my, gen);
}
__device__ __forceinline__ void bar_wait(const unsigned* base, unsigned gen){
  if (threadIdx.x < 64){
    for (;;){
      unsigned mn = 0xffffffffu;
      for (int i = (int)threadIdx.x; i < 8; i += 64){
        unsigned v = cohldu(base + i);
        mn = v < mn ? v : mn;
      }
      #pragma unroll
      for (int off = 32; off; off >>= 1){
        unsigned o2 = (unsigned)__shfl_xor((int)mn, off);
        mn = o2 < mn ? o2 : mn;
      }
      if (mn >= gen) break;
      __builtin_amdgcn_s_sleep(1);
    }
    __builtin_amdgcn_sched_barrier(0);
  }
  __syncthreads();
}

// ---------------------------------------------------------------------------
// f32 (strided) -> bf16 hi (+ optional lo residual). cols==512.
__global__ void split_kernel(const float* __restrict__ src, int src_ld, int src_coff,
                             int rows,
                             unsigned short* __restrict__ dhi, unsigned short* __restrict__ dlo,
                             int dst_ld, int dst_coff)
{
  int n = rows << 9;
  for (int i = blockIdx.x*blockDim.x + threadIdx.x; i < n; i += gridDim.x*blockDim.x){
    int r = i >> 9, c = i & 511;
    float x = src[(size_t)r*src_ld + src_coff + c];
    unsigned short h = f_to_bf16(x);
    dhi[(size_t)r*dst_ld + dst_coff + c] = h;
    if (dlo) dlo[(size_t)r*dst_ld + dst_coff + c] = f_to_bf16(x - bf16_to_f(h));
  }
}

// plain f32 -> bf16 convert (grid-stride)
__global__ void f2bf_kernel(const float* __restrict__ src,
                            unsigned short* __restrict__ dst, size_t n)
{
  for (size_t i = blockIdx.x*(size_t)blockDim.x + threadIdx.x; i < n;
       i += (size_t)gridDim.x*blockDim.x)
    dst[i] = f_to_bf16(src[i]);
}

// Embedding gather -> bf16 hi/lo rows (row = b*T + t)
__global__ void embed_kernel(const int* __restrict__ caps, const float* __restrict__ embW,
                             unsigned short* __restrict__ ehi, unsigned short* __restrict__ elo)
{
  int row = blockIdx.x;
  int cap = caps[row];
  const float* s = embW + (size_t)cap*E;
  for (int e = threadIdx.x; e < E; e += blockDim.x){
    float x = s[e];
    unsigned short h = f_to_bf16(x);
    ehi[(size_t)row*E + e] = h;
    elo[(size_t)row*E + e] = f_to_bf16(x - bf16_to_f(h));
  }
}

// mean over P, then h0 -> hgrp[0][b], c0 -> c_state
__global__ __launch_bounds__(512) void prep_kernel(
    const float* __restrict__ feats,
    const float* __restrict__ inith_W, const float* __restrict__ inith_b,
    const float* __restrict__ initc_W, const float* __restrict__ initc_b,
    float* __restrict__ hgrp, float* __restrict__ c_state)
{
  __shared__ float mf[E];
  const int b = blockIdx.x, tid = threadIdx.x;
  const float* fb = feats + (size_t)b*P*E + tid;
  float s = 0.f;
  for (int p = 0; p < P; ++p) s += fb[(size_t)p*E];
  mf[tid] = s * (1.0f/196.0f);
  __syncthreads();
  const float* wh = inith_W + (size_t)tid*E;
  const float* wc = initc_W + (size_t)tid*E;
  float h0 = inith_b[tid], c0 = initc_b[tid];
  #pragma unroll 4
  for (int e = 0; e < E; e += 4){
    float4 a4 = *(const float4*)(wh + e);
    float4 b4 = *(const float4*)(wc + e);
    float4 m4 = *(const float4*)(mf + e);
    h0 += dot4(a4, m4);
    c0 += dot4(b4, m4);
  }
  hgrp[(size_t)b*512 + tid] = h0;
  c_state[b*512 + tid] = c0;
}

// WhT[k][j] = attn_W[j][E + k]
__global__ __launch_bounds__(256) void transpose_wh_kernel(
    const float* __restrict__ attn_W, float* __restrict__ WhT)
{
  __shared__ float tile[64][65];
  const int jt = blockIdx.x & 7, kt = blockIdx.x >> 3;
  const int tx = threadIdx.x & 63, ty = threadIdx.x >> 6;
  for (int r = ty; r < 64; r += 4)
    tile[r][tx] = attn_W[(size_t)(jt*64 + r)*(E+H) + E + kt*64 + tx];
  __syncthreads();
  for (int r = ty; r < 64; r += 4)
    WhT[(size_t)(kt*64 + r)*512 + jt*64 + tx] = tile[tx][r];
}

// Wpackh[sub][k][c] in BF16: k in [0,512) = Whh row of gate col; c in [0,256):
// gcol = (c>>6)*512 + sub*64 + (c&63). Coalesced repack.
__global__ __launch_bounds__(256) void pack_whh_kernel(
    const float* __restrict__ Whh, unsigned short* __restrict__ Wpackh)
{
  __shared__ float tile[64][65];
  const int sub = blockIdx.x & 7, cg = (blockIdx.x >> 3) & 3, kg = blockIdx.x >> 5;
  const int tx = threadIdx.x & 63, ty = threadIdx.x >> 6;
  const int kbase = kg*64;
  for (int cl = ty; cl < 64; cl += 4){
    const int c = cg*64 + cl;
    const int gcol = (c >> 6)*512 + sub*64 + (c & 63);
    tile[cl][tx] = Whh[(size_t)gcol*512 + kbase + tx];
  }
  __syncthreads();
  for (int kk = ty; kk < 64; kk += 4)
    Wpackh[((size_t)sub*512 + kbase + kk)*256 + cg*64 + tx] = f_to_bf16(tile[tx][kk]);
}

// ---------------------------------------------------------------------------
// m97-style bf16 GEMM: C = sum_passes A_p (MxK) * B_p(NxK)^T [+bias]
__global__ __launch_bounds__(256) void gemm_bt_kernel(
    const unsigned short* __restrict__ A0, const unsigned short* __restrict__ A1,
    const unsigned short* __restrict__ A2,
    const unsigned short* __restrict__ B0, const unsigned short* __restrict__ B1,
    const unsigned short* __restrict__ B2,
    float* __restrict__ Cc, const float* __restrict__ bias,
    int N, int K, int npasses, int mt, int swz)
{
  __shared__ __align__(16) unsigned short Al[128*32];
  __shared__ __align__(16) unsigned short Bl[128*32];
  const int tid = threadIdx.x;
  const int wid = tid >> 6, l = tid & 63;
  int f = blockIdx.x;
  if (swz) f = (f & 7)*((int)gridDim.x >> 3) + (f >> 3);
  const int m0 = (f % mt)*128, n0 = (f / mt)*128;
  const int wr = wid >> 1, wc = wid & 1;

  f4v acc[4][4];
  #pragma unroll
  for (int i = 0; i < 4; ++i)
    #pragma unroll
    for (int j = 0; j < 4; ++j) acc[i][j] = (f4v){0.f,0.f,0.f,0.f};

  const int s0 = tid, s1 = tid + 256;
  const int r0 = s0 >> 2, g0 = (s0 & 3) ^ ((r0 >> 1) & 3);
  const int r1 = s1 >> 2, g1 = (s1 & 3) ^ ((r1 >> 1) & 3);
  const int la = l & 15, ch = l >> 4;

  for (int pass = 0; pass < npasses; ++pass){
    const unsigned short* Ap = pass == 0 ? A0 : (pass == 1 ? A1 : A2);
    const unsigned short* Bp = pass == 0 ? B0 : (pass == 1 ? B1 : B2);
    for (int k0 = 0; k0 < K; k0 += 32){
      __syncthreads();
      load_lds16(Ap + (size_t)(m0 + r0)*K + k0 + g0*8, Al + s0*8);
      load_lds16(Ap + (size_t)(m0 + r1)*K + k0 + g1*8, Al + s1*8);
      load_lds16(Bp + (size_t)(n0 + r0)*K + k0 + g0*8, Bl + s0*8);
      load_lds16(Bp + (size_t)(n0 + r1)*K + k0 + g1*8, Bl + s1*8);
      __syncthreads();
      s8v av[4], bv[4];
      #pragma unroll
      for (int mi = 0; mi < 4; ++mi){
        int row = wr*64 + mi*16 + la;
        int cs = ch ^ ((row >> 1) & 3);
        av[mi] = *(const s8v*)(Al + (row*4 + cs)*8);
      }
      #pragma unroll
      for (int ni = 0; ni < 4; ++ni){
        int row = wc*64 + ni*16 + la;
        int cs = ch ^ ((row >> 1) & 3);
        bv[ni] = *(const s8v*)(Bl + (row*4 + cs)*8);
      }
      #pragma unroll
      for (int mi = 0; mi < 4; ++mi)
        #pragma unroll
        for (int ni = 0; ni < 4; ++ni)
          acc[mi][ni] = __builtin_amdgcn_mfma_f32_16x16x32_bf16(av[mi], bv[ni], acc[mi][ni], 0, 0, 0);
    }
  }
  #pragma unroll
  for (int mi = 0; mi < 4; ++mi){
    int row = m0 + wr*64 + mi*16 + (l >> 4)*4;
    #pragma unroll
    for (int ni = 0; ni < 4; ++ni){
      int col = n0 + wc*64 + ni*16 + (l & 15);
      float bb = bias ? bias[col] : 0.0f;
      #pragma unroll
      for (int r = 0; r < 4; ++r)
        Cc[(size_t)(row + r)*N + col] = acc[mi][ni][r] + bb;
    }
  }
}

// ---------------------------------------------------------------------------
// Persistent loop kernel, batch-local groups, zero global sync, 2 minis/step.
// blk = sub*32 + b => the 8 group members share one XCD (minis XCD-local).
// Block owns j-slice sub*64..+64 x 4 gates of ITS batch. FW streamed in BF16
// (17MB/step, partially L2-resident, hidden under barrier windows).
// Per step: [ge pf] A,B | arrive1 | D-h | wait1 | softmax | D-ctx | update |
//           arrive3 | hall stores | wait3.
__global__ __launch_bounds__(512, 1) void loop_kernel(
    const float* __restrict__ feat_proj,
    const float* __restrict__ WhT, const float* __restrict__ attn_b,
    const float* __restrict__ v_w, const unsigned short* __restrict__ Wpackh,
    const unsigned short* __restrict__ FWb, const float* __restrict__ gates_emb,
    const float* __restrict__ b_ih, const float* __restrict__ b_hh,
    float* __restrict__ hgrp,          // [T+1][B][512]
    const float* __restrict__ c_init,
    float* __restrict__ sps,           // [T][B][200][8]
    unsigned short* __restrict__ hall_h, unsigned short* __restrict__ hall_l,
    unsigned* __restrict__ fm1, unsigned* __restrict__ fm3)
{
  __shared__ float hs[512];
  __shared__ float hwl[64];
  __shared__ float partA[8][72];
  __shared__ float aux[256];
  __shared__ float biasl[256];
  __shared__ float red[512];
  __shared__ float smx, sinv;

  const int blk = blockIdx.x, tid = threadIdx.x;
  const int b = blk & 31, sub = blk >> 5;       // XCD-local group mapping
  const int l = tid & 63, wv = tid >> 6;

  // ---- prologue ----
  float wreg[64];
  #pragma unroll
  for (int kk = 0; kk < 64; ++kk)
    wreg[kk] = WhT[(size_t)(wv*64 + kk)*512 + sub*64 + l];
  float fpreg[25];
  #pragma unroll
  for (int i = 0; i < 25; ++i){
    const int p = wv + i*8;
    fpreg[i] = (p < P) ? feat_proj[((size_t)b*P + p)*512 + sub*64 + l] : 0.f;
  }
  for (int c = tid; c < 256; c += NT){
    const int gcol = (c >> 6)*512 + sub*64 + (c & 63);
    biasl[c] = b_ih[gcol] + b_hh[gcol];
  }
  const float vl = v_w[sub*64 + l];
  const float ab = (tid < 64) ? attn_b[sub*64 + tid] : 0.f;
  float c_reg = 0.f;
  if (tid < 64) c_reg = c_init[b*512 + sub*64 + tid];

  // phase-D decomposition: thread = (dc: block-local col, kh: half)
  const int dc = tid & 255;
  const int kh = tid >> 8;
  const int gcol_d = (dc >> 6)*512 + sub*64 + (dc & 63);
  const unsigned short* wp_h = Wpackh + ((size_t)sub*512 + kh*256)*256 + dc;
  const unsigned short* fw_th = FWb + ((size_t)b*P + kh*98)*2048 + gcol_d;
  __syncthreads();

  for (int t = 0; t < T; ++t){
    const unsigned gen = (unsigned)(t + 1);

    // ---- gates_emb prefetch (hidden under A/B/D-h) ----
    float gepre[4];
    if (tid < 64){
      const float* ge = gates_emb + ((size_t)b*T + t)*2048;
      #pragma unroll
      for (int g = 0; g < 4; ++g) gepre[g] = ge[g*512 + sub*64 + tid];
    }

    // ---- A: hWh[b][sub*64..+64) (register WhT slice x LDS-broadcast h) ----
    hs[tid] = hgrp[((size_t)t*B + b)*512 + tid];      // plain (time-indexed)
    __syncthreads();
    {
      const float* hk = hs + wv*64;
      float a = 0.f;
      #pragma unroll
      for (int kk = 0; kk < 64; ++kk) a += hk[kk] * wreg[kk];
      partA[wv][l] = a;
    }
    __syncthreads();
    if (tid < 64){
      float s = ab;
      #pragma unroll
      for (int k = 0; k < 8; ++k) s += partA[k][tid];
      hwl[tid] = s;
    }
    __syncthreads();

    // ---- B: partial scores over own j-slice (feat_proj from registers) ----
    {
      const float hj = hwl[l];
      float* spw = sps + (size_t)(t*B + b)*1600 + sub;
      #pragma unroll
      for (int i = 0; i < 25; ++i){
        const int p = wv + i*8;
        if (p >= P) break;
        float e2 = vl * fast_tanh(fpreg[i] + hj);
        #pragma unroll
        for (int off = 32; off; off >>= 1) e2 += __shfl_xor(e2, off);
        if (l == 0) cohstore(spw + p*8, e2);
      }
    }
    bar_arrive(fm1 + b*8 + sub, gen);

    // ---- D-h: Whh(bf16)-part dots (needs only hs; hides mini1 window) ----
    float acch0 = 0.f, acch1 = 0.f, acch2 = 0.f, acch3 = 0.f;
    {
      const float* hk = hs + kh*256;
      #pragma unroll 8
      for (int k = 0; k < 256; k += 4){
        acch0 += bf16_to_f(wp_h[(size_t)(k+0)*256]) * hk[k+0];
        acch1 += bf16_to_f(wp_h[(size_t)(k+1)*256]) * hk[k+1];
        acch2 += bf16_to_f(wp_h[(size_t)(k+2)*256]) * hk[k+2];
        acch3 += bf16_to_f(wp_h[(size_t)(k+3)*256]) * hk[k+3];
      }
    }
    bar_wait(fm1 + b*8, gen);

    // ---- softmax (redundant x8, all operands local/plain) ----
    {
      float sc_v = -1e30f;
      if (tid < P){
        const float* sp = sps + (size_t)(t*B + b)*1600 + tid*8;
        float4 q0 = *(const float4*)sp, q1 = *(const float4*)(sp + 4);
        sc_v = (q0.x + q0.y + q0.z + q0.w) + (q1.x + q1.y + q1.z + q1.w);
      }
      if (tid < 256) aux[tid] = sc_v;
      __syncthreads();
      if (tid < 64){
        float m = -1e30f;
        #pragma unroll
        for (int i = 0; i < 4; ++i) m = fmaxf(m, aux[tid + i*64]);
        #pragma unroll
        for (int off = 32; off; off >>= 1) m = fmaxf(m, __shfl_xor(m, off));
        if (tid == 0) smx = m;
      }
      __syncthreads();
      float al = (tid < P) ? __expf(sc_v - smx) : 0.f;
      if (tid < 256) aux[tid] = al;
      __syncthreads();
      if (tid < 64){
        float s = 0.f;
        #pragma unroll
        for (int i = 0; i < 4; ++i) s += aux[tid + i*64];
        #pragma unroll
        for (int off = 32; off; off >>= 1) s += __shfl_xor(s, off);
        if (tid == 0) sinv = 1.0f/s;
      }
      __syncthreads();
    }

    // ---- D-ctx: rank-P contraction against streamed bf16 FW ----
    float accc = 0.f;
    {
      const float* ax = aux + kh*98;
      #pragma unroll 7
      for (int i = 0; i < 98; ++i)
        accc += ax[i] * bf16_to_f(fw_th[(size_t)i*2048]);
    }
    red[dc*2 + kh] = ((acch0 + acch1) + (acch2 + acch3)) + accc*sinv;
    __syncthreads();

    // ---- LSTM update ----
    if (tid < 64){
      float gv[4];
      #pragma unroll
      for (int g = 0; g < 4; ++g){
        const int c = g*64 + tid;
        gv[g] = red[c*2] + red[c*2 + 1] + biasl[c] + gepre[g];
      }
      const float i_ = sigmoidf_(gv[0]);
      const float f_ = sigmoidf_(gv[1]);
      const float g_ = fast_tanh(gv[2]);
      const float o_ = sigmoidf_(gv[3]);
      const int j = sub*64 + tid;
      const float c_new = f_*c_reg + i_*g_;
      const float h_new = o_*fast_tanh(c_new);
      c_reg = c_new;
      cohstore(hgrp + ((size_t)(t+1)*B + b)*512 + j, h_new);
      const unsigned short hh = f_to_bf16(h_new);
      aux[tid] = __uint_as_float(((unsigned)hh << 16) |
                 (unsigned)f_to_bf16(h_new - bf16_to_f(hh)));
    }
    bar_arrive(fm3 + b*8 + sub, gen);
    if (tid < 64){
      const unsigned pk = __float_as_uint(aux[tid]);
      const int j = sub*64 + tid;
      hall_h[((size_t)b*T + t)*512 + j] = (unsigned short)(pk >> 16);
      hall_l[((size_t)b*T + t)*512 + j] = (unsigned short)(pk & 0xffffu);
    }
    bar_wait(fm3 + b*8, gen);
  }
}

// ---------------------------------------------------------------------------
extern "C" void kernel_launch(void* const* d_in, const int* in_sizes, int n_in,
                              void* d_out, int out_size, void* d_ws, size_t ws_size,
                              hipStream_t stream)
{
  (void)in_sizes; (void)n_in; (void)out_size;
  const float* features = (const float*)d_in[0];
  const int*   captions = (const int*)d_in[1];
  const float* embed_W  = (const float*)d_in[2];
  const float* attn_W   = (const float*)d_in[3];
  const float* attn_b   = (const float*)d_in[4];
  const float* v_w      = (const float*)d_in[5];
  const float* W_ih     = (const float*)d_in[6];
  const float* W_hh     = (const float*)d_in[7];
  const float* b_ih     = (const float*)d_in[8];
  const float* b_hh     = (const float*)d_in[9];
  const float* lin_W    = (const float*)d_in[10];
  const float* lin_b    = (const float*)d_in[11];
  const float* inith_W  = (const float*)d_in[12];
  const float* inith_b  = (const float*)d_in[13];
  const float* initc_W  = (const float*)d_in[14];
  const float* initc_b  = (const float*)d_in[15];

  // "early" scratch in d_out (~125MB; all dead before final logits GEMM)
  char* o = (char*)d_out;
  unsigned short* feat_hi   = (unsigned short*)o; o += (size_t)(B*P)*E*2;   // 6.4MB
  unsigned short* feat_lo   = (unsigned short*)o; o += (size_t)(B*P)*E*2;   // 6.4MB
  unsigned short* Wf_bf     = (unsigned short*)o; o += (size_t)H*E*2;       // 0.5MB
  float*          feat_proj = (float*)o;          o += (size_t)(B*P)*H*4;   // 12.9MB
  unsigned short* emb_hi    = (unsigned short*)o; o += (size_t)(B*T)*E*2;   // 1.05MB
  unsigned short* emb_lo    = (unsigned short*)o; o += (size_t)(B*T)*E*2;
  unsigned short* Wihe_hi   = (unsigned short*)o; o += (size_t)2048*512*2;  // 2.1MB
  unsigned short* Wihe_lo   = (unsigned short*)o; o += (size_t)2048*512*2;
  unsigned short* Wihc_hi   = (unsigned short*)o; o += (size_t)2048*512*2;  // 2.1MB
  unsigned short* Wihc_lo   = (unsigned short*)o; o += (size_t)2048*512*2;
  float*          gates_emb = (float*)o;          o += (size_t)(B*T)*2048*4;// 8.4MB
  unsigned short* Wpackh    = (unsigned short*)o; o += (size_t)8*512*256*2; // 2.1MB
  float*          FW        = (float*)o;          o += (size_t)(B*P)*2048*4;// 51.4MB
  unsigned short* FWb       = (unsigned short*)o; o += (size_t)(B*P)*2048*2;// 25.7MB

  // persistent scratch in d_ws
  const size_t SZ_LIN  = (size_t)V*H*2;               // 32.77MB
  const size_t SZ_HALL = (size_t)(B*T)*H*2;           // 1MB
  const size_t SZ_HG   = (size_t)(T+1)*B*512*4;       // 2.16MB
  const size_t SZ_SPS  = (size_t)T*B*200*8*4;         // 6.55MB
  const size_t SZ_ST   = (size_t)B*H*4;               // 64KB
  const size_t SZ_WHT  = (size_t)H*H*4;               // 1MB
  const size_t SZ_FLG  = 4096;
  const size_t need_wo = SZ_LIN + 2*SZ_HALL + SZ_HG + SZ_SPS + SZ_ST + SZ_WHT + SZ_FLG;
  const bool three = (ws_size >= need_wo + SZ_LIN);

  char* w = (char*)d_ws;
  unsigned short* lin_hi  = (unsigned short*)w; w += SZ_LIN;
  unsigned short* lin_lo  = (unsigned short*)w; if (three) w += SZ_LIN;
  unsigned short* hall_hi = (unsigned short*)w; w += SZ_HALL;
  unsigned short* hall_lo = (unsigned short*)w; w += SZ_HALL;
  float*          hgrp    = (float*)w;          w += SZ_HG;
  float*          sps     = (float*)w;          w += SZ_SPS;
  float*          c_state = (float*)w;          w += SZ_ST;
  float*          WhT_ws  = (float*)w;          w += SZ_WHT;
  unsigned*       flags   = (unsigned*)w;       w += SZ_FLG;
  unsigned* fm1 = flags;           // [256] indexed [b*8+sub]
  unsigned* fm3 = flags + 256;     // [256]

  // --- conversions / gathers / packs / init ---
  split_kernel<<<2048, 256, 0, stream>>>(features, E, 0, B*P, feat_hi, feat_lo, E, 0);
  split_kernel<<<256, 256, 0, stream>>>(attn_W, E+H, 0, H, Wf_bf, nullptr, E, 0);
  split_kernel<<<2048, 256, 0, stream>>>(lin_W, 512, 0, V, lin_hi, three ? lin_lo : nullptr, 512, 0);
  split_kernel<<<1024, 256, 0, stream>>>(W_ih, 1024, 0, 2048, Wihe_hi, Wihe_lo, 512, 0);
  split_kernel<<<1024, 256, 0, stream>>>(W_ih, 1024, 512, 2048, Wihc_hi, Wihc_lo, 512, 0);
  embed_kernel<<<B*T, 256, 0, stream>>>(captions, embed_W, emb_hi, emb_lo);
  prep_kernel<<<B, 512, 0, stream>>>(features, inith_W, inith_b, initc_W, initc_b,
                                     hgrp, c_state);
  transpose_wh_kernel<<<64, 256, 0, stream>>>(attn_W, WhT_ws);
  pack_whh_kernel<<<256, 256, 0, stream>>>(W_hh, Wpackh);
  hipMemsetAsync(flags, 0, SZ_FLG, stream);

  // feat_proj = features @ Wf^T (bf16 1-pass; error damped through tanh/softmax)
  gemm_bt_kernel<<<(B*P/128)*(E/128), 256, 0, stream>>>(
      feat_hi, feat_hi, feat_hi, Wf_bf, Wf_bf, Wf_bf,
      feat_proj, nullptr, E, E, 1, B*P/128, 0);
  // gates_emb = emb @ W_ih[:, :512]^T (bf16x3)
  gemm_bt_kernel<<<(B*T/128)*(2048/128), 256, 0, stream>>>(
      emb_hi, emb_lo, emb_hi, Wihe_hi, Wihe_hi, Wihe_lo,
      gates_emb, nullptr, 2048, 512, 3, B*T/128, 1);
  // FW = features @ W_ih[:, 512:]^T (bf16x3), then convert to bf16
  gemm_bt_kernel<<<(B*P/128)*(2048/128), 256, 0, stream>>>(
      feat_hi, feat_lo, feat_hi, Wihc_hi, Wihc_hi, Wihc_lo,
      FW, nullptr, 2048, 512, 3, B*P/128, 1);
  f2bf_kernel<<<2048, 256, 0, stream>>>(FW, FWb, (size_t)(B*P)*2048);

  // --- recurrence: one persistent kernel, zero global sync, 2 minis/step ---
  loop_kernel<<<NB, NT, 0, stream>>>(
      feat_proj, WhT_ws, attn_b, v_w, Wpackh, FWb, gates_emb, b_ih, b_hh,
      hgrp, c_state, sps, hall_hi, hall_lo, fm1, fm3);

  // --- logits = h_all @ lin_W^T + lin_b (bf16x3, XCD-swizzled grid) ---
  gemm_bt_kernel<<<(V/128)*(B*T/128), 256, 0, stream>>>(
      hall_hi, hall_lo, hall_hi, lin_hi, lin_hi, three ? lin_lo : lin_hi,
      (float*)d_out, lin_b, V, H, three ? 3 : 2, B*T/128, 1);
}